// Round 1
// baseline (5025.684 us; speedup 1.0000x reference)
//
#include <hip/hip_runtime.h>
#include <cstddef>
#include <cstdint>

#define T_ 2048
#define H_ 1024
#define NH_ 16
#define LCTX 512

__device__ __forceinline__ float sgm(float x) { return 1.0f / (1.0f + expf(-x)); }

#define BM 64
#define BN 64
#define BK 16

// AMODE: 0 plain A, 1 hidden_states token-shift lerp, 2 resampled-context token-shift lerp,
//        3 tanh(A), 4 sigmoid(A)
// EPI:   0 plain store, 1 w-lora (LOGW*sigmoid(x+b)), 2 sigmoid(x+b), 3 v-first gate lerp
template <int AMODE, int EPI>
__global__ __launch_bounds__(256) void gemm_k(
    const float* __restrict__ Asrc, const float* __restrict__ Bsrc,
    float* __restrict__ Cdst, int M, int N, int K,
    const float* __restrict__ xvec,
    const float* __restrict__ aux1, const float* __restrict__ aux2,
    const float* __restrict__ bias)
{
    __shared__ float As[BK][BM + 4];
    __shared__ float Bs[BK][BN + 4];
    const int tid = threadIdx.x;
    const int bm = blockIdx.x * BM;
    const int bn = blockIdx.y * BN;
    const int arow = tid >> 2;
    const int acol = (tid & 3) * 4;
    const int brow = tid >> 4;
    const int bcol = (tid & 15) * 4;
    const int tm = (tid >> 4) * 4;
    const int tn = (tid & 15) * 4;
    float acc[4][4] = {{0.0f}};

    for (int k0 = 0; k0 < K; k0 += BK) {
        // ---- A tile (BM x BK), generated on the fly ----
        {
            const int gm = bm + arow;
            const int kc = k0 + acol;
            float v0, v1, v2, v3;
            if (AMODE == 0 || AMODE == 3 || AMODE == 4) {
                const float4 c = *(const float4*)(Asrc + (size_t)gm * K + kc);
                v0 = c.x; v1 = c.y; v2 = c.z; v3 = c.w;
                if (AMODE == 3) { v0 = tanhf(v0); v1 = tanhf(v1); v2 = tanhf(v2); v3 = tanhf(v3); }
                if (AMODE == 4) { v0 = sgm(v0); v1 = sgm(v1); v2 = sgm(v2); v3 = sgm(v3); }
            } else if (AMODE == 1) {
                const float4 c = *(const float4*)(Asrc + (size_t)gm * K + kc);
                float p0 = 0, p1 = 0, p2 = 0, p3 = 0;
                if ((gm & (T_ - 1)) != 0) {
                    const float4 p = *(const float4*)(Asrc + (size_t)(gm - 1) * K + kc);
                    p0 = p.x; p1 = p.y; p2 = p.z; p3 = p.w;
                }
                const float4 xv = *(const float4*)(xvec + kc);
                v0 = c.x + (p0 - c.x) * xv.x;
                v1 = c.y + (p1 - c.y) * xv.y;
                v2 = c.z + (p2 - c.z) * xv.z;
                v3 = c.w + (p3 - c.w) * xv.w;
            } else { // AMODE == 2 : linear-resampled context, token-shift lerp
                const int b = gm >> 11;
                const int t = gm & (T_ - 1);
                const float scale = (float)(511.0 / 2047.0);
                float tf = (float)t * scale;
                int lo = (int)tf;
                float f = tf - (float)lo;
                int hi = lo + 1; if (hi > LCTX - 1) hi = LCTX - 1;
                const float4 cl = *(const float4*)(Asrc + (size_t)(b * LCTX + lo) * 1024 + kc);
                const float4 ch = *(const float4*)(Asrc + (size_t)(b * LCTX + hi) * 1024 + kc);
                float c0 = cl.x + (ch.x - cl.x) * f;
                float c1 = cl.y + (ch.y - cl.y) * f;
                float c2 = cl.z + (ch.z - cl.z) * f;
                float c3 = cl.w + (ch.w - cl.w) * f;
                float p0 = 0, p1 = 0, p2 = 0, p3 = 0;
                if (t != 0) {
                    float tf2 = (float)(t - 1) * scale;
                    int lo2 = (int)tf2;
                    float f2 = tf2 - (float)lo2;
                    int hi2 = lo2 + 1; if (hi2 > LCTX - 1) hi2 = LCTX - 1;
                    const float4 pl = *(const float4*)(Asrc + (size_t)(b * LCTX + lo2) * 1024 + kc);
                    const float4 ph = *(const float4*)(Asrc + (size_t)(b * LCTX + hi2) * 1024 + kc);
                    p0 = pl.x + (ph.x - pl.x) * f2;
                    p1 = pl.y + (ph.y - pl.y) * f2;
                    p2 = pl.z + (ph.z - pl.z) * f2;
                    p3 = pl.w + (ph.w - pl.w) * f2;
                }
                const float4 xv = *(const float4*)(xvec + kc);
                v0 = c0 + (p0 - c0) * xv.x;
                v1 = c1 + (p1 - c1) * xv.y;
                v2 = c2 + (p2 - c2) * xv.z;
                v3 = c3 + (p3 - c3) * xv.w;
            }
            As[acol + 0][arow] = v0;
            As[acol + 1][arow] = v1;
            As[acol + 2][arow] = v2;
            As[acol + 3][arow] = v3;
        }
        // ---- B tile (BK x BN) ----
        {
            const int gn = bn + bcol;
            float b0 = 0, b1 = 0, b2 = 0, b3 = 0;
            if (gn < N) {
                const float4 bb = *(const float4*)(Bsrc + (size_t)(k0 + brow) * N + gn);
                b0 = bb.x; b1 = bb.y; b2 = bb.z; b3 = bb.w;
            }
            Bs[brow][bcol + 0] = b0; Bs[brow][bcol + 1] = b1;
            Bs[brow][bcol + 2] = b2; Bs[brow][bcol + 3] = b3;
        }
        __syncthreads();
        #pragma unroll
        for (int kk2 = 0; kk2 < BK; ++kk2) {
            const float4 a4 = *(const float4*)&As[kk2][tm];
            const float4 b4 = *(const float4*)&Bs[kk2][tn];
            acc[0][0] += a4.x * b4.x; acc[0][1] += a4.x * b4.y; acc[0][2] += a4.x * b4.z; acc[0][3] += a4.x * b4.w;
            acc[1][0] += a4.y * b4.x; acc[1][1] += a4.y * b4.y; acc[1][2] += a4.y * b4.z; acc[1][3] += a4.y * b4.w;
            acc[2][0] += a4.z * b4.x; acc[2][1] += a4.z * b4.y; acc[2][2] += a4.z * b4.z; acc[2][3] += a4.z * b4.w;
            acc[3][0] += a4.w * b4.x; acc[3][1] += a4.w * b4.y; acc[3][2] += a4.w * b4.z; acc[3][3] += a4.w * b4.w;
        }
        __syncthreads();
    }
    #pragma unroll
    for (int i = 0; i < 4; ++i) {
        const int gm = bm + tm + i;
        #pragma unroll
        for (int j = 0; j < 4; ++j) {
            const int gn = bn + tn + j;
            if (gn >= N) continue;
            const size_t idx = (size_t)gm * N + gn;
            float x = acc[i][j];
            if (EPI == 0) {
                Cdst[idx] = x;
            } else if (EPI == 1) {
                Cdst[idx] = -0.6065306597126334f * sgm(x + bias[gn]);
            } else if (EPI == 2) {
                Cdst[idx] = sgm(x + bias[gn]);
            } else {
                float gate = sgm(x + bias[gn]);
                float vt = aux1[idx];
                Cdst[idx] = vt + gate * (aux2[idx] - vt);
            }
        }
    }
}

// kk = normalize_per_head(k * k_k); k <- k * (1 + (a-1)*k_a)   (in place)
__global__ __launch_bounds__(256) void prep_k(
    float* __restrict__ k, const float* __restrict__ a,
    const float* __restrict__ k_k, const float* __restrict__ k_a,
    float* __restrict__ kk)
{
    const int gid = blockIdx.x * 256 + threadIdx.x;
    const int j = gid & 63;
    const int h = (gid >> 6) & (NH_ - 1);
    const int ch = h * 64 + j;
    const float kv = k[gid];
    float kkv = kv * k_k[ch];
    float ss = kkv * kkv;
    #pragma unroll
    for (int m = 32; m; m >>= 1) ss += __shfl_xor(ss, m, 64);
    const float nrm = fmaxf(sqrtf(ss), 1e-12f);
    kk[gid] = kkv / nrm;
    const float av = a[gid];
    k[gid] = kv * (1.0f + (av - 1.0f) * k_a[ch]);
}

// One wave per (b,h); thread i owns state row S[i][0..63].
__global__ __launch_bounds__(64) void rwkv_rec(
    const float* __restrict__ r, const float* __restrict__ w,
    const float* __restrict__ k, const float* __restrict__ v,
    const float* __restrict__ kk, const float* __restrict__ a,
    float* __restrict__ o)
{
    const int bh = blockIdx.x;
    const int lane = threadIdx.x;
    const int b = bh >> 4, h = bh & (NH_ - 1);
    __shared__ __align__(16) float ew[64];
    __shared__ __align__(16) float ah[64];
    __shared__ __align__(16) float bhh[64];
    __shared__ __align__(16) float kh[64];
    __shared__ __align__(16) float rh[64];
    float S[64];
    #pragma unroll
    for (int j = 0; j < 64; ++j) S[j] = 0.0f;

    size_t idx = ((size_t)b * T_ * NH_ + h) * 64 + lane;
    for (int t = 0; t < T_; ++t, idx += NH_ * 64) {
        const float wv = w[idx];
        const float kkv = kk[idx];
        const float av = a[idx];
        const float kv = k[idx];
        const float rv = r[idx];
        const float vv = v[idx];
        ew[lane] = expf(wv);
        ah[lane] = -kkv;
        bhh[lane] = kkv * av;
        kh[lane] = kv;
        rh[lane] = rv;
        __syncthreads();
        float sa = 0.0f;
        const float4* A4 = (const float4*)ah;
        #pragma unroll
        for (int jv = 0; jv < 16; ++jv) {
            const float4 q = A4[jv];
            sa += S[4 * jv + 0] * q.x + S[4 * jv + 1] * q.y + S[4 * jv + 2] * q.z + S[4 * jv + 3] * q.w;
        }
        float oi = 0.0f;
        const float4* E4 = (const float4*)ew;
        const float4* B4 = (const float4*)bhh;
        const float4* K4 = (const float4*)kh;
        const float4* R4 = (const float4*)rh;
        #pragma unroll
        for (int jv = 0; jv < 16; ++jv) {
            const float4 e = E4[jv], bb = B4[jv], kq = K4[jv], rr = R4[jv];
            float s;
            s = S[4 * jv + 0] * e.x + sa * bb.x + vv * kq.x; S[4 * jv + 0] = s; oi += s * rr.x;
            s = S[4 * jv + 1] * e.y + sa * bb.y + vv * kq.y; S[4 * jv + 1] = s; oi += s * rr.y;
            s = S[4 * jv + 2] * e.z + sa * bb.z + vv * kq.z; S[4 * jv + 2] = s; oi += s * rr.z;
            s = S[4 * jv + 3] * e.w + sa * bb.w + vv * kq.w; S[4 * jv + 3] = s; oi += s * rr.w;
        }
        o[idx] = oi;
        __syncthreads();
    }
}

// GroupNorm(64) + r_k readout + output gate -> og
__global__ __launch_bounds__(256) void postproc(
    const float* __restrict__ o, const float* __restrict__ r, const float* __restrict__ k,
    const float* __restrict__ v, const float* __restrict__ g, const float* __restrict__ r_k,
    const float* __restrict__ gn_w, const float* __restrict__ gn_b,
    float* __restrict__ og)
{
    const int gid = blockIdx.x * 256 + threadIdx.x;
    const int i = gid & 63;
    const int h = (gid >> 6) & (NH_ - 1);
    const int ch = h * 64 + i;
    const float ov = o[gid];
    float s1 = ov, s2 = ov * ov;
    float term = r[gid] * k[gid] * r_k[ch];
    #pragma unroll
    for (int m = 32; m; m >>= 1) {
        s1 += __shfl_xor(s1, m, 64);
        s2 += __shfl_xor(s2, m, 64);
        term += __shfl_xor(term, m, 64);
    }
    const float mu = s1 * (1.0f / 64.0f);
    const float var = s2 * (1.0f / 64.0f) - mu * mu;
    const float on = (ov - mu) * rsqrtf(var + 6.4e-4f);
    const float outv = on * gn_w[ch] + gn_b[ch] + term * v[gid];
    og[gid] = outv * g[gid];
}

extern "C" void kernel_launch(void* const* d_in, const int* in_sizes, int n_in,
                              void* d_out, int out_size, void* d_ws, size_t ws_size,
                              hipStream_t stream)
{
    const float* hs      = (const float*)d_in[0];
    const float* context = (const float*)d_in[1];
    const float* v_first = (const float*)d_in[2];
    const float* x_r = (const float*)d_in[3];
    const float* x_w = (const float*)d_in[4];
    const float* x_k = (const float*)d_in[5];
    const float* x_v = (const float*)d_in[6];
    const float* x_a = (const float*)d_in[7];
    const float* x_g = (const float*)d_in[8];
    const float* k_k = (const float*)d_in[9];
    const float* k_a = (const float*)d_in[10];
    const float* r_k = (const float*)d_in[11];
    const float* W_r = (const float*)d_in[12];
    const float* W_k = (const float*)d_in[13];
    const float* W_v = (const float*)d_in[14];
    const float* W_o = (const float*)d_in[15];
    const float* W_cond = (const float*)d_in[16];
    const float* wA = (const float*)d_in[17];
    const float* wB = (const float*)d_in[18];
    const float* wb = (const float*)d_in[19];
    const float* aA = (const float*)d_in[20];
    const float* aB = (const float*)d_in[21];
    const float* ab = (const float*)d_in[22];
    const float* gA = (const float*)d_in[23];
    const float* gB = (const float*)d_in[24];
    const float* vA = (const float*)d_in[25];
    const float* vB = (const float*)d_in[26];
    const float* vb = (const float*)d_in[27];
    const float* gn_w = (const float*)d_in[28];
    const float* gn_b = (const float*)d_in[29];

    float* ws = (float*)d_ws;
    float* cp    = ws;                  // [1024,1024] ctx projection
    float* rbuf  = cp + 1048576;        // [4096,1024]
    float* kbuf  = rbuf + 4194304;      // [4096,1024] raw k -> k_final (in place)
    float* vtmp  = kbuf + 4194304;      // [4096,1024] raw v
    float* wbuf  = vtmp + 4194304;      // [4096,1024] log-decay w; later reused as og
    float* abuf  = wbuf + 4194304;      // [4096,1024]
    float* gbuf  = abuf + 4194304;      // [4096,1024]
    float* kkbuf = gbuf + 4194304;      // [4096,1024]
    float* vbuf  = kkbuf + 4194304;     // [4096,1024] final v
    float* obuf  = vbuf + 4194304;      // [4096,1024]
    float* w1b   = obuf + 4194304;      // [4096,64]
    float* a1b   = w1b + 262144;        // [4096,64]
    float* g1b   = a1b + 262144;        // [4096,128]
    float* v1b   = g1b + 524288;        // [4096,16]
    (void)in_sizes; (void)n_in; (void)out_size; (void)ws_size;

    const dim3 blk(256);
    // ctx projection: [B*Lctx,768] @ [768,1024]
    gemm_k<0, 0><<<dim3(16, 16), blk, 0, stream>>>(context, W_cond, cp, 1024, 1024, 768,
                                                   nullptr, nullptr, nullptr, nullptr);
    // main projections
    gemm_k<1, 0><<<dim3(64, 16), blk, 0, stream>>>(hs, W_r, rbuf, 4096, 1024, 1024, x_r, nullptr, nullptr, nullptr);
    gemm_k<2, 0><<<dim3(64, 16), blk, 0, stream>>>(cp, W_k, kbuf, 4096, 1024, 1024, x_k, nullptr, nullptr, nullptr);
    gemm_k<2, 0><<<dim3(64, 16), blk, 0, stream>>>(cp, W_v, vtmp, 4096, 1024, 1024, x_v, nullptr, nullptr, nullptr);
    // LoRA stage 1
    gemm_k<1, 0><<<dim3(64, 1), blk, 0, stream>>>(hs, wA, w1b, 4096, 64, 1024, x_w, nullptr, nullptr, nullptr);
    gemm_k<1, 0><<<dim3(64, 1), blk, 0, stream>>>(hs, aA, a1b, 4096, 64, 1024, x_a, nullptr, nullptr, nullptr);
    gemm_k<1, 0><<<dim3(64, 2), blk, 0, stream>>>(hs, gA, g1b, 4096, 128, 1024, x_g, nullptr, nullptr, nullptr);
    gemm_k<2, 0><<<dim3(64, 1), blk, 0, stream>>>(cp, vA, v1b, 4096, 16, 1024, x_v, nullptr, nullptr, nullptr);
    // LoRA stage 2
    gemm_k<3, 1><<<dim3(64, 16), blk, 0, stream>>>(w1b, wB, wbuf, 4096, 1024, 64, nullptr, nullptr, nullptr, wb);
    gemm_k<0, 2><<<dim3(64, 16), blk, 0, stream>>>(a1b, aB, abuf, 4096, 1024, 64, nullptr, nullptr, nullptr, ab);
    gemm_k<4, 0><<<dim3(64, 16), blk, 0, stream>>>(g1b, gB, gbuf, 4096, 1024, 128, nullptr, nullptr, nullptr, nullptr);
    gemm_k<0, 3><<<dim3(64, 16), blk, 0, stream>>>(v1b, vB, vbuf, 4096, 1024, 16, nullptr, vtmp, v_first, vb);
    // kk normalization + k_a adjust
    prep_k<<<dim3(16384), blk, 0, stream>>>(kbuf, abuf, k_k, k_a, kkbuf);
    // sequential recurrence
    rwkv_rec<<<dim3(32), dim3(64), 0, stream>>>(rbuf, wbuf, kbuf, vbuf, kkbuf, abuf, obuf);
    // groupnorm + readout + gate (og into wbuf, dead after recurrence)
    postproc<<<dim3(16384), blk, 0, stream>>>(obuf, rbuf, kbuf, vbuf, gbuf, r_k, gn_w, gn_b, wbuf);
    // output projection
    gemm_k<0, 0><<<dim3(64, 16), blk, 0, stream>>>(wbuf, W_o, (float*)d_out, 4096, 1024, 1024,
                                                   nullptr, nullptr, nullptr, nullptr);
}

// Round 2
// 1713.331 us; speedup vs baseline: 2.9333x; 2.9333x over previous
//
#include <hip/hip_runtime.h>
#include <cstddef>
#include <cstdint>

#define T_ 2048
#define H_ 1024
#define NH_ 16
#define LCTX 512
#define NC 32     // number of chunks
#define CL 64     // chunk length (NC*CL == T_)

__device__ __forceinline__ float sgm(float x) { return 1.0f / (1.0f + expf(-x)); }

#define BM 64
#define BN 64
#define BK 16

// AMODE: 0 plain A, 1 hidden_states token-shift lerp, 2 resampled-context token-shift lerp,
//        3 tanh(A), 4 sigmoid(A)
// EPI:   0 plain store, 1 w-lora (LOGW*sigmoid(x+b)), 2 sigmoid(x+b), 3 v-first gate lerp
template <int AMODE, int EPI>
__global__ __launch_bounds__(256) void gemm_k(
    const float* __restrict__ Asrc, const float* __restrict__ Bsrc,
    float* __restrict__ Cdst, int M, int N, int K,
    const float* __restrict__ xvec,
    const float* __restrict__ aux1, const float* __restrict__ aux2,
    const float* __restrict__ bias)
{
    __shared__ float As[BK][BM + 4];
    __shared__ float Bs[BK][BN + 4];
    const int tid = threadIdx.x;
    const int bm = blockIdx.x * BM;
    const int bn = blockIdx.y * BN;
    const int arow = tid >> 2;
    const int acol = (tid & 3) * 4;
    const int brow = tid >> 4;
    const int bcol = (tid & 15) * 4;
    const int tm = (tid >> 4) * 4;
    const int tn = (tid & 15) * 4;
    float acc[4][4] = {{0.0f}};

    for (int k0 = 0; k0 < K; k0 += BK) {
        // ---- A tile (BM x BK), generated on the fly ----
        {
            const int gm = bm + arow;
            const int kc = k0 + acol;
            float v0, v1, v2, v3;
            if (AMODE == 0 || AMODE == 3 || AMODE == 4) {
                const float4 c = *(const float4*)(Asrc + (size_t)gm * K + kc);
                v0 = c.x; v1 = c.y; v2 = c.z; v3 = c.w;
                if (AMODE == 3) { v0 = tanhf(v0); v1 = tanhf(v1); v2 = tanhf(v2); v3 = tanhf(v3); }
                if (AMODE == 4) { v0 = sgm(v0); v1 = sgm(v1); v2 = sgm(v2); v3 = sgm(v3); }
            } else if (AMODE == 1) {
                const float4 c = *(const float4*)(Asrc + (size_t)gm * K + kc);
                float p0 = 0, p1 = 0, p2 = 0, p3 = 0;
                if ((gm & (T_ - 1)) != 0) {
                    const float4 p = *(const float4*)(Asrc + (size_t)(gm - 1) * K + kc);
                    p0 = p.x; p1 = p.y; p2 = p.z; p3 = p.w;
                }
                const float4 xv = *(const float4*)(xvec + kc);
                v0 = c.x + (p0 - c.x) * xv.x;
                v1 = c.y + (p1 - c.y) * xv.y;
                v2 = c.z + (p2 - c.z) * xv.z;
                v3 = c.w + (p3 - c.w) * xv.w;
            } else { // AMODE == 2 : linear-resampled context, token-shift lerp
                const int b = gm >> 11;
                const int t = gm & (T_ - 1);
                const float scale = (float)(511.0 / 2047.0);
                float tf = (float)t * scale;
                int lo = (int)tf;
                float f = tf - (float)lo;
                int hi = lo + 1; if (hi > LCTX - 1) hi = LCTX - 1;
                const float4 cl = *(const float4*)(Asrc + (size_t)(b * LCTX + lo) * 1024 + kc);
                const float4 ch = *(const float4*)(Asrc + (size_t)(b * LCTX + hi) * 1024 + kc);
                float c0 = cl.x + (ch.x - cl.x) * f;
                float c1 = cl.y + (ch.y - cl.y) * f;
                float c2 = cl.z + (ch.z - cl.z) * f;
                float c3 = cl.w + (ch.w - cl.w) * f;
                float p0 = 0, p1 = 0, p2 = 0, p3 = 0;
                if (t != 0) {
                    float tf2 = (float)(t - 1) * scale;
                    int lo2 = (int)tf2;
                    float f2 = tf2 - (float)lo2;
                    int hi2 = lo2 + 1; if (hi2 > LCTX - 1) hi2 = LCTX - 1;
                    const float4 pl = *(const float4*)(Asrc + (size_t)(b * LCTX + lo2) * 1024 + kc);
                    const float4 ph = *(const float4*)(Asrc + (size_t)(b * LCTX + hi2) * 1024 + kc);
                    p0 = pl.x + (ph.x - pl.x) * f2;
                    p1 = pl.y + (ph.y - pl.y) * f2;
                    p2 = pl.z + (ph.z - pl.z) * f2;
                    p3 = pl.w + (ph.w - pl.w) * f2;
                }
                const float4 xv = *(const float4*)(xvec + kc);
                v0 = c0 + (p0 - c0) * xv.x;
                v1 = c1 + (p1 - c1) * xv.y;
                v2 = c2 + (p2 - c2) * xv.z;
                v3 = c3 + (p3 - c3) * xv.w;
            }
            As[acol + 0][arow] = v0;
            As[acol + 1][arow] = v1;
            As[acol + 2][arow] = v2;
            As[acol + 3][arow] = v3;
        }
        // ---- B tile (BK x BN) ----
        {
            const int gn = bn + bcol;
            float b0 = 0, b1 = 0, b2 = 0, b3 = 0;
            if (gn < N) {
                const float4 bb = *(const float4*)(Bsrc + (size_t)(k0 + brow) * N + gn);
                b0 = bb.x; b1 = bb.y; b2 = bb.z; b3 = bb.w;
            }
            Bs[brow][bcol + 0] = b0; Bs[brow][bcol + 1] = b1;
            Bs[brow][bcol + 2] = b2; Bs[brow][bcol + 3] = b3;
        }
        __syncthreads();
        #pragma unroll
        for (int kk2 = 0; kk2 < BK; ++kk2) {
            const float4 a4 = *(const float4*)&As[kk2][tm];
            const float4 b4 = *(const float4*)&Bs[kk2][tn];
            acc[0][0] += a4.x * b4.x; acc[0][1] += a4.x * b4.y; acc[0][2] += a4.x * b4.z; acc[0][3] += a4.x * b4.w;
            acc[1][0] += a4.y * b4.x; acc[1][1] += a4.y * b4.y; acc[1][2] += a4.y * b4.z; acc[1][3] += a4.y * b4.w;
            acc[2][0] += a4.z * b4.x; acc[2][1] += a4.z * b4.y; acc[2][2] += a4.z * b4.z; acc[2][3] += a4.z * b4.w;
            acc[3][0] += a4.w * b4.x; acc[3][1] += a4.w * b4.y; acc[3][2] += a4.w * b4.z; acc[3][3] += a4.w * b4.w;
        }
        __syncthreads();
    }
    #pragma unroll
    for (int i = 0; i < 4; ++i) {
        const int gm = bm + tm + i;
        #pragma unroll
        for (int j = 0; j < 4; ++j) {
            const int gn = bn + tn + j;
            if (gn >= N) continue;
            const size_t idx = (size_t)gm * N + gn;
            float x = acc[i][j];
            if (EPI == 0) {
                Cdst[idx] = x;
            } else if (EPI == 1) {
                Cdst[idx] = -0.6065306597126334f * sgm(x + bias[gn]);
            } else if (EPI == 2) {
                Cdst[idx] = sgm(x + bias[gn]);
            } else {
                float gate = sgm(x + bias[gn]);
                float vt = aux1[idx];
                Cdst[idx] = vt + gate * (aux2[idx] - vt);
            }
        }
    }
}

// kk = normalize_per_head(k * k_k); k <- k * (1 + (a-1)*k_a)   (in place)
__global__ __launch_bounds__(256) void prep_k(
    float* __restrict__ k, const float* __restrict__ a,
    const float* __restrict__ k_k, const float* __restrict__ k_a,
    float* __restrict__ kk)
{
    const int gid = blockIdx.x * 256 + threadIdx.x;
    const int j = gid & 63;
    const int h = (gid >> 6) & (NH_ - 1);
    const int ch = h * 64 + j;
    const float kv = k[gid];
    float kkv = kv * k_k[ch];
    float ss = kkv * kkv;
    #pragma unroll
    for (int m = 32; m; m >>= 1) ss += __shfl_xor(ss, m, 64);
    const float nrm = fmaxf(sqrtf(ss), 1e-12f);
    kk[gid] = kkv / nrm;
    const float av = a[gid];
    k[gid] = kv * (1.0f + (av - 1.0f) * k_a[ch]);
}

// ---------------- Chunked RWKV7 scan ----------------
// Transition: S_t = S_{t-1} (diag(e_t) + a_t b_t^T) + v_t k_t^T  (right-multiply)
// Phase A: per (b,h,chunk): P_c = prod of M_t, U_c = chunk contribution from zero state.
__global__ __launch_bounds__(64, 1) void chunk_AU(
    const float* __restrict__ w, const float* __restrict__ k,
    const float* __restrict__ v, const float* __restrict__ kk,
    const float* __restrict__ a,
    float* __restrict__ Pbuf, float* __restrict__ Ubuf)
{
    const int bid = blockIdx.x;
    const int c = bid & (NC - 1);
    const int bh = bid >> 5;
    const int b = bh >> 4, h = bh & (NH_ - 1);
    const int lane = threadIdx.x;
    __shared__ __align__(16) float ew[64];
    __shared__ __align__(16) float ah[64];
    __shared__ __align__(16) float bhh[64];
    __shared__ __align__(16) float kh[64];

    float Q[64], Uu[64];
    #pragma unroll
    for (int j = 0; j < 64; ++j) { Q[j] = 0.0f; Uu[j] = 0.0f; }
    Q[lane] = 1.0f;

    size_t idx = (((size_t)b * T_ + (size_t)c * CL) * NH_ + h) * 64 + lane;
    float wv = w[idx], kkv = kk[idx], av = a[idx], kv = k[idx], vv = v[idx];

    for (int t = 0; t < CL; ++t) {
        ew[lane] = expf(wv);
        ah[lane] = -kkv;
        bhh[lane] = kkv * av;
        kh[lane] = kv;
        const float vcur = vv;
        __syncthreads();
        if (t + 1 < CL) {
            idx += NH_ * 64;
            wv = w[idx]; kkv = kk[idx]; av = a[idx]; kv = k[idx]; vv = v[idx];
        }
        float qa0 = 0, qa1 = 0, qa2 = 0, qa3 = 0;
        float sa0 = 0, sa1 = 0, sa2 = 0, sa3 = 0;
        const float4* A4 = (const float4*)ah;
        #pragma unroll
        for (int jv = 0; jv < 16; ++jv) {
            const float4 q = A4[jv];
            qa0 += Q[4 * jv + 0] * q.x; qa1 += Q[4 * jv + 1] * q.y;
            qa2 += Q[4 * jv + 2] * q.z; qa3 += Q[4 * jv + 3] * q.w;
            sa0 += Uu[4 * jv + 0] * q.x; sa1 += Uu[4 * jv + 1] * q.y;
            sa2 += Uu[4 * jv + 2] * q.z; sa3 += Uu[4 * jv + 3] * q.w;
        }
        const float Qa = (qa0 + qa1) + (qa2 + qa3);
        const float Sa = (sa0 + sa1) + (sa2 + sa3);
        const float4* E4 = (const float4*)ew;
        const float4* B4 = (const float4*)bhh;
        const float4* K4 = (const float4*)kh;
        #pragma unroll
        for (int jv = 0; jv < 16; ++jv) {
            const float4 e = E4[jv], bb = B4[jv], kq = K4[jv];
            Q[4 * jv + 0] = Q[4 * jv + 0] * e.x + Qa * bb.x;
            Q[4 * jv + 1] = Q[4 * jv + 1] * e.y + Qa * bb.y;
            Q[4 * jv + 2] = Q[4 * jv + 2] * e.z + Qa * bb.z;
            Q[4 * jv + 3] = Q[4 * jv + 3] * e.w + Qa * bb.w;
            Uu[4 * jv + 0] = Uu[4 * jv + 0] * e.x + Sa * bb.x + vcur * kq.x;
            Uu[4 * jv + 1] = Uu[4 * jv + 1] * e.y + Sa * bb.y + vcur * kq.y;
            Uu[4 * jv + 2] = Uu[4 * jv + 2] * e.z + Sa * bb.z + vcur * kq.z;
            Uu[4 * jv + 3] = Uu[4 * jv + 3] * e.w + Sa * bb.w + vcur * kq.w;
        }
        __syncthreads();
    }
    // store P (row lane) and U (row lane), flat [bh][c][i*64+j]
    float* Pd = Pbuf + (((size_t)bh * NC + c) * 64 + lane) * 64;
    float* Ud = Ubuf + (((size_t)bh * NC + c) * 64 + lane) * 64;
    #pragma unroll
    for (int jv = 0; jv < 16; ++jv) {
        ((float4*)Pd)[jv] = make_float4(Q[4 * jv + 0], Q[4 * jv + 1], Q[4 * jv + 2], Q[4 * jv + 3]);
        ((float4*)Ud)[jv] = make_float4(Uu[4 * jv + 0], Uu[4 * jv + 1], Uu[4 * jv + 2], Uu[4 * jv + 3]);
    }
}

// Phase B: sequential over chunks (parallel over b,h): S_{c+1} = S_c P_c + U_c.
// Stores chunk-start state S_c for every chunk.
__global__ __launch_bounds__(256) void chunk_scan(
    const float* __restrict__ Pbuf, const float* __restrict__ Ubuf,
    float* __restrict__ Scbuf)
{
    const int bh = blockIdx.x;
    const int tid = threadIdx.x;
    __shared__ __align__(16) float S_lds[64 * 65];
    __shared__ __align__(16) float P_lds[64 * 64];
    __shared__ __align__(16) float U_lds[64 * 65];

    for (int idx = tid; idx < 4096; idx += 256)
        S_lds[(idx >> 6) * 65 + (idx & 63)] = 0.0f;
    __syncthreads();

    const int i = tid & 63;
    const int jq = tid >> 6;
    const int jbase = jq * 16;

    for (int c = 0; c < NC; ++c) {
        const size_t base = ((size_t)bh * NC + c) * 4096;
        // store chunk-start state (coalesced)
        for (int idx = tid; idx < 4096; idx += 256)
            Scbuf[base + idx] = S_lds[(idx >> 6) * 65 + (idx & 63)];
        // load P, U (coalesced)
        for (int idx = tid; idx < 4096; idx += 256) {
            P_lds[idx] = Pbuf[base + idx];
            U_lds[(idx >> 6) * 65 + (idx & 63)] = Ubuf[base + idx];
        }
        __syncthreads();
        float acc[16];
        #pragma unroll
        for (int jj = 0; jj < 16; ++jj) acc[jj] = 0.0f;
        for (int kx = 0; kx < 64; ++kx) {
            const float s = S_lds[i * 65 + kx];
            const float4* Prow = (const float4*)&P_lds[kx * 64 + jbase];
            const float4 p0 = Prow[0], p1 = Prow[1], p2 = Prow[2], p3 = Prow[3];
            acc[0] += s * p0.x; acc[1] += s * p0.y; acc[2] += s * p0.z; acc[3] += s * p0.w;
            acc[4] += s * p1.x; acc[5] += s * p1.y; acc[6] += s * p1.z; acc[7] += s * p1.w;
            acc[8] += s * p2.x; acc[9] += s * p2.y; acc[10] += s * p2.z; acc[11] += s * p2.w;
            acc[12] += s * p3.x; acc[13] += s * p3.y; acc[14] += s * p3.z; acc[15] += s * p3.w;
        }
        __syncthreads();
        #pragma unroll
        for (int jj = 0; jj < 16; ++jj)
            S_lds[i * 65 + jbase + jj] = acc[jj] + U_lds[i * 65 + jbase + jj];
        __syncthreads();
    }
}

// Phase C: per (b,h,chunk): run the exact recurrence from S_c, emit outputs.
__global__ __launch_bounds__(64, 1) void chunk_out(
    const float* __restrict__ r, const float* __restrict__ w,
    const float* __restrict__ k, const float* __restrict__ v,
    const float* __restrict__ kk, const float* __restrict__ a,
    const float* __restrict__ Scbuf, float* __restrict__ o)
{
    const int bid = blockIdx.x;
    const int c = bid & (NC - 1);
    const int bh = bid >> 5;
    const int b = bh >> 4, h = bh & (NH_ - 1);
    const int lane = threadIdx.x;
    __shared__ __align__(16) float ew[64];
    __shared__ __align__(16) float ah[64];
    __shared__ __align__(16) float bhh[64];
    __shared__ __align__(16) float kh[64];
    __shared__ __align__(16) float rh[64];

    float S[64];
    const float* Srow = Scbuf + (((size_t)bh * NC + c) * 64 + lane) * 64;
    #pragma unroll
    for (int jv = 0; jv < 16; ++jv) {
        const float4 s4 = ((const float4*)Srow)[jv];
        S[4 * jv + 0] = s4.x; S[4 * jv + 1] = s4.y; S[4 * jv + 2] = s4.z; S[4 * jv + 3] = s4.w;
    }

    size_t idx = (((size_t)b * T_ + (size_t)c * CL) * NH_ + h) * 64 + lane;
    float wv = w[idx], kkv = kk[idx], av = a[idx], kv = k[idx], rv = r[idx], vv = v[idx];

    for (int t = 0; t < CL; ++t) {
        ew[lane] = expf(wv);
        ah[lane] = -kkv;
        bhh[lane] = kkv * av;
        kh[lane] = kv;
        rh[lane] = rv;
        const float vcur = vv;
        const size_t oidx = idx;
        __syncthreads();
        if (t + 1 < CL) {
            idx += NH_ * 64;
            wv = w[idx]; kkv = kk[idx]; av = a[idx]; kv = k[idx]; rv = r[idx]; vv = v[idx];
        }
        float sa0 = 0, sa1 = 0, sa2 = 0, sa3 = 0;
        const float4* A4 = (const float4*)ah;
        #pragma unroll
        for (int jv = 0; jv < 16; ++jv) {
            const float4 q = A4[jv];
            sa0 += S[4 * jv + 0] * q.x; sa1 += S[4 * jv + 1] * q.y;
            sa2 += S[4 * jv + 2] * q.z; sa3 += S[4 * jv + 3] * q.w;
        }
        const float sa = (sa0 + sa1) + (sa2 + sa3);
        float o0 = 0, o1 = 0, o2 = 0, o3 = 0;
        const float4* E4 = (const float4*)ew;
        const float4* B4 = (const float4*)bhh;
        const float4* K4 = (const float4*)kh;
        const float4* R4 = (const float4*)rh;
        #pragma unroll
        for (int jv = 0; jv < 16; ++jv) {
            const float4 e = E4[jv], bb = B4[jv], kq = K4[jv], rr = R4[jv];
            float s;
            s = S[4 * jv + 0] * e.x + sa * bb.x + vcur * kq.x; S[4 * jv + 0] = s; o0 += s * rr.x;
            s = S[4 * jv + 1] * e.y + sa * bb.y + vcur * kq.y; S[4 * jv + 1] = s; o1 += s * rr.y;
            s = S[4 * jv + 2] * e.z + sa * bb.z + vcur * kq.z; S[4 * jv + 2] = s; o2 += s * rr.z;
            s = S[4 * jv + 3] * e.w + sa * bb.w + vcur * kq.w; S[4 * jv + 3] = s; o3 += s * rr.w;
        }
        o[oidx] = (o0 + o1) + (o2 + o3);
        __syncthreads();
    }
}

// GroupNorm(64) + r_k readout + output gate -> og
__global__ __launch_bounds__(256) void postproc(
    const float* __restrict__ o, const float* __restrict__ r, const float* __restrict__ k,
    const float* __restrict__ v, const float* __restrict__ g, const float* __restrict__ r_k,
    const float* __restrict__ gn_w, const float* __restrict__ gn_b,
    float* __restrict__ og)
{
    const int gid = blockIdx.x * 256 + threadIdx.x;
    const int i = gid & 63;
    const int h = (gid >> 6) & (NH_ - 1);
    const int ch = h * 64 + i;
    const float ov = o[gid];
    float s1 = ov, s2 = ov * ov;
    float term = r[gid] * k[gid] * r_k[ch];
    #pragma unroll
    for (int m = 32; m; m >>= 1) {
        s1 += __shfl_xor(s1, m, 64);
        s2 += __shfl_xor(s2, m, 64);
        term += __shfl_xor(term, m, 64);
    }
    const float mu = s1 * (1.0f / 64.0f);
    const float var = s2 * (1.0f / 64.0f) - mu * mu;
    const float on = (ov - mu) * rsqrtf(var + 6.4e-4f);
    const float outv = on * gn_w[ch] + gn_b[ch] + term * v[gid];
    og[gid] = outv * g[gid];
}

extern "C" void kernel_launch(void* const* d_in, const int* in_sizes, int n_in,
                              void* d_out, int out_size, void* d_ws, size_t ws_size,
                              hipStream_t stream)
{
    const float* hs      = (const float*)d_in[0];
    const float* context = (const float*)d_in[1];
    const float* v_first = (const float*)d_in[2];
    const float* x_r = (const float*)d_in[3];
    const float* x_w = (const float*)d_in[4];
    const float* x_k = (const float*)d_in[5];
    const float* x_v = (const float*)d_in[6];
    const float* x_a = (const float*)d_in[7];
    const float* x_g = (const float*)d_in[8];
    const float* k_k = (const float*)d_in[9];
    const float* k_a = (const float*)d_in[10];
    const float* r_k = (const float*)d_in[11];
    const float* W_r = (const float*)d_in[12];
    const float* W_k = (const float*)d_in[13];
    const float* W_v = (const float*)d_in[14];
    const float* W_o = (const float*)d_in[15];
    const float* W_cond = (const float*)d_in[16];
    const float* wA = (const float*)d_in[17];
    const float* wB = (const float*)d_in[18];
    const float* wb = (const float*)d_in[19];
    const float* aA = (const float*)d_in[20];
    const float* aB = (const float*)d_in[21];
    const float* ab = (const float*)d_in[22];
    const float* gA = (const float*)d_in[23];
    const float* gB = (const float*)d_in[24];
    const float* vA = (const float*)d_in[25];
    const float* vB = (const float*)d_in[26];
    const float* vb = (const float*)d_in[27];
    const float* gn_w = (const float*)d_in[28];
    const float* gn_b = (const float*)d_in[29];

    float* ws = (float*)d_ws;
    float* cp    = ws;                  // [1024,1024] ctx projection
    float* rbuf  = cp + 1048576;        // [4096,1024]
    float* kbuf  = rbuf + 4194304;      // [4096,1024] raw k -> k_final (in place)
    float* vtmp  = kbuf + 4194304;      // [4096,1024] raw v; dead after v-lora gemm -> reused as Ubuf
    float* wbuf  = vtmp + 4194304;      // [4096,1024] log-decay w; later reused as og
    float* abuf  = wbuf + 4194304;      // [4096,1024]
    float* gbuf  = abuf + 4194304;      // [4096,1024]
    float* kkbuf = gbuf + 4194304;      // [4096,1024]
    float* vbuf  = kkbuf + 4194304;     // [4096,1024] final v
    float* obuf  = vbuf + 4194304;      // [4096,1024]
    float* w1b   = obuf + 4194304;      // [4096,64]
    float* a1b   = w1b + 262144;        // [4096,64]
    float* g1b   = a1b + 262144;        // [4096,128]
    float* v1b   = g1b + 524288;        // [4096,16]
    float* Pbuf  = v1b + 65536;         // [32bh][32c][64][64]
    float* Scbuf = Pbuf + 4194304;      // [32bh][32c][64][64]
    float* Ubuf  = vtmp;                // alias (vtmp dead by phase A)
    (void)in_sizes; (void)n_in; (void)out_size; (void)ws_size;

    const dim3 blk(256);
    // ctx projection: [B*Lctx,768] @ [768,1024]
    gemm_k<0, 0><<<dim3(16, 16), blk, 0, stream>>>(context, W_cond, cp, 1024, 1024, 768,
                                                   nullptr, nullptr, nullptr, nullptr);
    // main projections
    gemm_k<1, 0><<<dim3(64, 16), blk, 0, stream>>>(hs, W_r, rbuf, 4096, 1024, 1024, x_r, nullptr, nullptr, nullptr);
    gemm_k<2, 0><<<dim3(64, 16), blk, 0, stream>>>(cp, W_k, kbuf, 4096, 1024, 1024, x_k, nullptr, nullptr, nullptr);
    gemm_k<2, 0><<<dim3(64, 16), blk, 0, stream>>>(cp, W_v, vtmp, 4096, 1024, 1024, x_v, nullptr, nullptr, nullptr);
    // LoRA stage 1
    gemm_k<1, 0><<<dim3(64, 1), blk, 0, stream>>>(hs, wA, w1b, 4096, 64, 1024, x_w, nullptr, nullptr, nullptr);
    gemm_k<1, 0><<<dim3(64, 1), blk, 0, stream>>>(hs, aA, a1b, 4096, 64, 1024, x_a, nullptr, nullptr, nullptr);
    gemm_k<1, 0><<<dim3(64, 2), blk, 0, stream>>>(hs, gA, g1b, 4096, 128, 1024, x_g, nullptr, nullptr, nullptr);
    gemm_k<2, 0><<<dim3(64, 1), blk, 0, stream>>>(cp, vA, v1b, 4096, 16, 1024, x_v, nullptr, nullptr, nullptr);
    // LoRA stage 2
    gemm_k<3, 1><<<dim3(64, 16), blk, 0, stream>>>(w1b, wB, wbuf, 4096, 1024, 64, nullptr, nullptr, nullptr, wb);
    gemm_k<0, 2><<<dim3(64, 16), blk, 0, stream>>>(a1b, aB, abuf, 4096, 1024, 64, nullptr, nullptr, nullptr, ab);
    gemm_k<4, 0><<<dim3(64, 16), blk, 0, stream>>>(g1b, gB, gbuf, 4096, 1024, 128, nullptr, nullptr, nullptr, nullptr);
    gemm_k<0, 3><<<dim3(64, 16), blk, 0, stream>>>(v1b, vB, vbuf, 4096, 1024, 16, nullptr, vtmp, v_first, vb);
    // kk normalization + k_a adjust
    prep_k<<<dim3(16384), blk, 0, stream>>>(kbuf, abuf, k_k, k_a, kkbuf);
    // chunked recurrence: A (parallel), B (32-step scan), C (parallel)
    chunk_AU<<<dim3(1024), dim3(64), 0, stream>>>(wbuf, kbuf, vbuf, kkbuf, abuf, Pbuf, Ubuf);
    chunk_scan<<<dim3(32), blk, 0, stream>>>(Pbuf, Ubuf, Scbuf);
    chunk_out<<<dim3(1024), dim3(64), 0, stream>>>(rbuf, wbuf, kbuf, vbuf, kkbuf, abuf, Scbuf, obuf);
    // groupnorm + readout + gate (og into wbuf, dead after recurrence)
    postproc<<<dim3(16384), blk, 0, stream>>>(obuf, rbuf, kbuf, vbuf, gbuf, r_k, gn_w, gn_b, wbuf);
    // output projection
    gemm_k<0, 0><<<dim3(64, 16), blk, 0, stream>>>(wbuf, W_o, (float*)d_out, 4096, 1024, 1024,
                                                   nullptr, nullptr, nullptr, nullptr);
}

// Round 4
// 1335.464 us; speedup vs baseline: 3.7633x; 1.2829x over previous
//
#include <hip/hip_runtime.h>
#include <cstddef>
#include <cstdint>

#define T_ 2048
#define H_ 1024
#define NH_ 16
#define LCTX 512
#define NC 32     // number of chunks
#define CL 64     // chunk length (NC*CL == T_)

typedef __attribute__((ext_vector_type(4))) float f4;
typedef __attribute__((ext_vector_type(4))) unsigned short u16x4;
typedef __attribute__((ext_vector_type(8))) short bf16x8;
typedef __attribute__((ext_vector_type(4))) float f32x4;

#define REP16(X) X(0) X(1) X(2) X(3) X(4) X(5) X(6) X(7) X(8) X(9) X(10) X(11) X(12) X(13) X(14) X(15)

__device__ __forceinline__ float sgm(float x) { return 1.0f / (1.0f + expf(-x)); }

__device__ __forceinline__ f4 f4splat(float v) { f4 r; r.x = v; r.y = v; r.z = v; r.w = v; return r; }

__device__ __forceinline__ unsigned short f2bf(float x) {
    unsigned u = __float_as_uint(x);
    u += 0x7FFFu + ((u >> 16) & 1u);
    return (unsigned short)(u >> 16);
}
__device__ __forceinline__ float bf2f(unsigned short h) {
    return __uint_as_float(((unsigned)h) << 16);
}

// ---------------- weight transpose + split to bf16 hi/lo ----------------
// W [K][N] fp32  ->  Th, Tl [N][K] bf16-bits
__global__ __launch_bounds__(256) void wtrans(
    const float* __restrict__ W, unsigned short* __restrict__ Th,
    unsigned short* __restrict__ Tl, int K, int N)
{
    __shared__ float tile[32][33];
    const int k0 = blockIdx.x * 32, n0 = blockIdx.y * 32;
    const int t = threadIdx.x;
    const int r = t >> 3, c4 = (t & 7) * 4;
    f4 v = f4splat(0.0f);
    if (k0 + r < K && n0 + c4 < N)
        v = *(const f4*)(W + (size_t)(k0 + r) * N + n0 + c4);
    tile[r][c4 + 0] = v.x; tile[r][c4 + 1] = v.y;
    tile[r][c4 + 2] = v.z; tile[r][c4 + 3] = v.w;
    __syncthreads();
    if (n0 + r < N && k0 + c4 < K) {
        float x0 = tile[c4 + 0][r], x1 = tile[c4 + 1][r];
        float x2 = tile[c4 + 2][r], x3 = tile[c4 + 3][r];
        u16x4 hv, lv;
        hv.x = f2bf(x0); lv.x = f2bf(x0 - bf2f(hv.x));
        hv.y = f2bf(x1); lv.y = f2bf(x1 - bf2f(hv.y));
        hv.z = f2bf(x2); lv.z = f2bf(x2 - bf2f(hv.z));
        hv.w = f2bf(x3); lv.w = f2bf(x3 - bf2f(hv.w));
        *(u16x4*)(Th + (size_t)(n0 + r) * K + k0 + c4) = hv;
        *(u16x4*)(Tl + (size_t)(n0 + r) * K + k0 + c4) = lv;
    }
}

// ---------------- elementwise prep ----------------
// xr,xw,xa,xg = hs + (shift(hs)-hs)*x_*
__global__ __launch_bounds__(256) void hs_lerp4(
    const float* __restrict__ hs,
    const float* __restrict__ x_r, const float* __restrict__ x_w,
    const float* __restrict__ x_a, const float* __restrict__ x_g,
    float* __restrict__ xr, float* __restrict__ xw,
    float* __restrict__ xa, float* __restrict__ xg)
{
    const int gid = blockIdx.x * 256 + threadIdx.x;   // over 1,048,576 f4 chunks
    const int c4 = (gid & 255) * 4;
    const int row = gid >> 8;
    const int tt = row & (T_ - 1);
    const f4 cur = *(const f4*)(hs + (size_t)row * H_ + c4);
    f4 prev = f4splat(0.0f);
    if (tt) prev = *(const f4*)(hs + (size_t)(row - 1) * H_ + c4);
    const f4 d = prev - cur;
    const size_t o = (size_t)row * H_ + c4;
    *(f4*)(xr + o) = cur + d * (*(const f4*)(x_r + c4));
    *(f4*)(xw + o) = cur + d * (*(const f4*)(x_w + c4));
    *(f4*)(xa + o) = cur + d * (*(const f4*)(x_a + c4));
    *(f4*)(xg + o) = cur + d * (*(const f4*)(x_g + c4));
}

__device__ __forceinline__ f4 ctx_sample(const float* __restrict__ cp, int b, int t, int c4) {
    const float scale = (float)(511.0 / 2047.0);
    float tf = (float)t * scale;
    int lo = (int)tf;
    float f = tf - (float)lo;
    int hi = lo + 1; if (hi > LCTX - 1) hi = LCTX - 1;
    f4 cl = *(const f4*)(cp + (size_t)(b * LCTX + lo) * 1024 + c4);
    f4 ch = *(const f4*)(cp + (size_t)(b * LCTX + hi) * 1024 + c4);
    return cl + (ch - cl) * f;
}

// xk, xv from resampled context + token shift
__global__ __launch_bounds__(256) void ctx_lerp2(
    const float* __restrict__ cp,
    const float* __restrict__ x_k, const float* __restrict__ x_v,
    float* __restrict__ xk, float* __restrict__ xv)
{
    const int gid = blockIdx.x * 256 + threadIdx.x;
    const int c4 = (gid & 255) * 4;
    const int row = gid >> 8;
    const int b = row >> 11;
    const int tt = row & (T_ - 1);
    const f4 cur = ctx_sample(cp, b, tt, c4);
    f4 prev = f4splat(0.0f);
    if (tt) prev = ctx_sample(cp, b, tt - 1, c4);
    const f4 d = prev - cur;
    const size_t o = (size_t)row * H_ + c4;
    *(f4*)(xk + o) = cur + d * (*(const f4*)(x_k + c4));
    *(f4*)(xv + o) = cur + d * (*(const f4*)(x_v + c4));
}

// ---------------- MFMA GEMM: C = A(fp32) @ B, B pre-transposed/split bf16 ----------------
// split-bf16: acc += Ah*Bh + Ah*Bl + Al*Bh  (fp32-class accuracy)
// EPI: 0 plain, 1 LOGW*sgm(x+b), 2 sgm(x+b), 3 v-lerp, 4 tanh, 5 sgm
template <int BN, int EPI>
__global__ __launch_bounds__(256) void mgemm(
    const float* __restrict__ A, const unsigned short* __restrict__ BTh,
    const unsigned short* __restrict__ BTl, float* __restrict__ C,
    int M, int N, int K,
    const float* __restrict__ bias, const float* __restrict__ aux1,
    const float* __restrict__ aux2)
{
    constexpr int NI = BN / 32;   // n-subtiles per wave
    __shared__ __align__(16) unsigned short Ah[8][4][16][8];
    __shared__ __align__(16) unsigned short Al[8][4][16][8];
    __shared__ __align__(16) unsigned short Bh[BN / 16][4][16][8];
    __shared__ __align__(16) unsigned short Bl[BN / 16][4][16][8];
    const int tid = threadIdx.x;
    const int lane = tid & 63;
    const int wave = tid >> 6;
    const int bm = blockIdx.x * 128;
    const int bn = blockIdx.y * BN;
    const int wm = (wave >> 1) * 64;
    const int wn = (wave & 1) * (BN / 2);
    const int g = lane >> 4, rr = lane & 15;

    f32x4 acc[4][NI];
    #pragma unroll
    for (int mi = 0; mi < 4; ++mi)
        #pragma unroll
        for (int ni = 0; ni < NI; ++ni)
            acc[mi][ni] = (f32x4)(0.0f);

    for (int k0 = 0; k0 < K; k0 += 32) {
        // ---- stage A tile 128x32 fp32 -> hi/lo bf16 in fragment order ----
        #pragma unroll
        for (int it = 0; it < 4; ++it) {
            const int idx = tid + it * 256;           // 0..1023
            const int row = idx >> 3;
            const int kt = (idx & 7) * 4;
            const int gk = k0 + kt;
            f4 v = f4splat(0.0f);
            if (gk < K) v = *(const f4*)(A + (size_t)(bm + row) * K + gk);
            u16x4 hv, lv;
            hv.x = f2bf(v.x); lv.x = f2bf(v.x - bf2f(hv.x));
            hv.y = f2bf(v.y); lv.y = f2bf(v.y - bf2f(hv.y));
            hv.z = f2bf(v.z); lv.z = f2bf(v.z - bf2f(hv.z));
            hv.w = f2bf(v.w); lv.w = f2bf(v.w - bf2f(hv.w));
            const int gg = (kt >> 2) & 3, e0 = (kt >> 4) * 4;
            *(u16x4*)&Ah[row >> 4][gg][row & 15][e0] = hv;
            *(u16x4*)&Al[row >> 4][gg][row & 15][e0] = lv;
        }
        // ---- stage B tile BNx32 from pre-split B^T [N][K] ----
        #pragma unroll
        for (int it = 0; it < BN / 32; ++it) {
            const int idx = tid + it * 256;           // 0..BN*8-1
            const int n = idx >> 3;
            const int kt = (idx & 7) * 4;
            const int gk = k0 + kt;
            const int gn = bn + n;
            u16x4 hv, lv;
            hv.x = hv.y = hv.z = hv.w = 0;
            lv.x = lv.y = lv.z = lv.w = 0;
            if (gn < N && gk < K) {
                hv = *(const u16x4*)(BTh + (size_t)gn * K + gk);
                lv = *(const u16x4*)(BTl + (size_t)gn * K + gk);
            }
            const int gg = (kt >> 2) & 3, e0 = (kt >> 4) * 4;
            *(u16x4*)&Bh[n >> 4][gg][n & 15][e0] = hv;
            *(u16x4*)&Bl[n >> 4][gg][n & 15][e0] = lv;
        }
        __syncthreads();
        bf16x8 a_h[4], a_l[4], b_h[NI], b_l[NI];
        #pragma unroll
        for (int mi = 0; mi < 4; ++mi) {
            a_h[mi] = *(const bf16x8*)&Ah[(wm >> 4) + mi][g][rr][0];
            a_l[mi] = *(const bf16x8*)&Al[(wm >> 4) + mi][g][rr][0];
        }
        #pragma unroll
        for (int ni = 0; ni < NI; ++ni) {
            b_h[ni] = *(const bf16x8*)&Bh[(wn >> 4) + ni][g][rr][0];
            b_l[ni] = *(const bf16x8*)&Bl[(wn >> 4) + ni][g][rr][0];
        }
        #pragma unroll
        for (int mi = 0; mi < 4; ++mi)
            #pragma unroll
            for (int ni = 0; ni < NI; ++ni) {
                acc[mi][ni] = __builtin_amdgcn_mfma_f32_16x16x32_bf16(a_h[mi], b_h[ni], acc[mi][ni], 0, 0, 0);
                acc[mi][ni] = __builtin_amdgcn_mfma_f32_16x16x32_bf16(a_h[mi], b_l[ni], acc[mi][ni], 0, 0, 0);
                acc[mi][ni] = __builtin_amdgcn_mfma_f32_16x16x32_bf16(a_l[mi], b_h[ni], acc[mi][ni], 0, 0, 0);
            }
        __syncthreads();
    }
    // ---- epilogue: C row = (lane>>4)*4 + reg, col = lane&15 (m89-verified) ----
    #pragma unroll
    for (int mi = 0; mi < 4; ++mi)
        #pragma unroll
        for (int ni = 0; ni < NI; ++ni)
            #pragma unroll
            for (int q = 0; q < 4; ++q) {
                const int grow = bm + wm + mi * 16 + g * 4 + q;
                const int gcol = bn + wn + ni * 16 + rr;
                if (gcol < N) {
                    const size_t o = (size_t)grow * N + gcol;
                    float x = acc[mi][ni][q];
                    if (EPI == 1) x = -0.6065306597126334f * sgm(x + bias[gcol]);
                    else if (EPI == 2) x = sgm(x + bias[gcol]);
                    else if (EPI == 3) {
                        float vt = aux1[o];
                        x = vt + sgm(x + bias[gcol]) * (aux2[o] - vt);
                    }
                    else if (EPI == 4) x = tanhf(x);
                    else if (EPI == 5) x = sgm(x);
                    C[o] = x;
                }
            }
}

// kk = normalize_per_head(k * k_k); k <- k * (1 + (a-1)*k_a)   (in place)
__global__ __launch_bounds__(256) void prep_k(
    float* __restrict__ k, const float* __restrict__ a,
    const float* __restrict__ k_k, const float* __restrict__ k_a,
    float* __restrict__ kk)
{
    const int gid = blockIdx.x * 256 + threadIdx.x;
    const int j = gid & 63;
    const int h = (gid >> 6) & (NH_ - 1);
    const int ch = h * 64 + j;
    const float kv = k[gid];
    float kkv = kv * k_k[ch];
    float ss = kkv * kkv;
    #pragma unroll
    for (int m = 32; m; m >>= 1) ss += __shfl_xor(ss, m, 64);
    const float nrm = fmaxf(sqrtf(ss), 1e-12f);
    kk[gid] = kkv / nrm;
    const float av = a[gid];
    k[gid] = kv * (1.0f + (av - 1.0f) * k_a[ch]);
}

// ---------------- Chunked RWKV7 scan ----------------
// S_t = S_{t-1} (diag(e_t) + a_t b_t^T) + v_t k_t^T
// Phase A: per (b,h,chunk): P_c = prod M_t (from I), U_c = chunk contribution from 0.
// State held in NAMED f4 registers (q0..q15,u0..u15) -> no scratch.
__global__ __launch_bounds__(64, 1) void chunk_AU(
    const float* __restrict__ w, const float* __restrict__ k,
    const float* __restrict__ v, const float* __restrict__ kk,
    const float* __restrict__ a,
    float* __restrict__ Pbuf, float* __restrict__ Ubuf)
{
    const int bid = blockIdx.x;
    const int c = bid & (NC - 1);
    const int bh = bid >> 5;
    const int b = bh >> 4, h = bh & (NH_ - 1);
    const int lane = threadIdx.x;
    __shared__ __align__(16) float ew_s[64], ah_s[64], bh_s[64], kh_s[64];

#define DECL_QU(i) f4 q##i = f4splat(0.0f), u##i = f4splat(0.0f);
    REP16(DECL_QU)
#undef DECL_QU
#define INIT_Q(i) \
    if (lane == 4*i+0) q##i.x = 1.0f; \
    else if (lane == 4*i+1) q##i.y = 1.0f; \
    else if (lane == 4*i+2) q##i.z = 1.0f; \
    else if (lane == 4*i+3) q##i.w = 1.0f;
    REP16(INIT_Q)
#undef INIT_Q

    size_t idx = (((size_t)b * T_ + (size_t)c * CL) * NH_ + h) * 64 + lane;
    float wv = w[idx], kkv = kk[idx], av = a[idx], kv = k[idx], vv = v[idx];

    for (int t = 0; t < CL; ++t) {
        ew_s[lane] = expf(wv);
        ah_s[lane] = -kkv;
        bh_s[lane] = kkv * av;
        kh_s[lane] = kv;
        const float vcur = vv;
        __syncthreads();
        if (t + 1 < CL) {
            idx += NH_ * 64;
            wv = w[idx]; kkv = kk[idx]; av = a[idx]; kv = k[idx]; vv = v[idx];
        }
        const f4* A4 = (const f4*)ah_s;
        f4 qa = f4splat(0.0f), ua = f4splat(0.0f);
#define DOT_(i) { f4 t4 = A4[i]; qa += q##i * t4; ua += u##i * t4; }
        REP16(DOT_)
#undef DOT_
        const float Qa = (qa.x + qa.y) + (qa.z + qa.w);
        const float Sa = (ua.x + ua.y) + (ua.z + ua.w);
        const f4* E4 = (const f4*)ew_s;
        const f4* B4 = (const f4*)bh_s;
        const f4* K4 = (const f4*)kh_s;
#define UPD_(i) { f4 e = E4[i], bb = B4[i], kq = K4[i]; \
        q##i = q##i * e + Qa * bb; \
        u##i = u##i * e + Sa * bb + vcur * kq; }
        REP16(UPD_)
#undef UPD_
        __syncthreads();
    }
    float* Pd = Pbuf + (((size_t)bh * NC + c) * 64 + lane) * 64;
    float* Ud = Ubuf + (((size_t)bh * NC + c) * 64 + lane) * 64;
#define ST_(i) ((f4*)Pd)[i] = q##i; ((f4*)Ud)[i] = u##i;
    REP16(ST_)
#undef ST_
}

// Phase B: sequential over chunks (parallel over b,h): S_{c+1} = S_c P_c + U_c.
__global__ __launch_bounds__(256) void chunk_scan(
    const float* __restrict__ Pbuf, const float* __restrict__ Ubuf,
    float* __restrict__ Scbuf)
{
    const int bh = blockIdx.x;
    const int tid = threadIdx.x;
    __shared__ __align__(16) float S_lds[64 * 65];
    __shared__ __align__(16) float P_lds[64 * 64];
    __shared__ __align__(16) float U_lds[64 * 65];

    for (int idx = tid; idx < 4096; idx += 256)
        S_lds[(idx >> 6) * 65 + (idx & 63)] = 0.0f;
    __syncthreads();

    const int i = tid & 63;
    const int jq = tid >> 6;
    const int jbase = jq * 16;

    for (int c = 0; c < NC; ++c) {
        const size_t base = ((size_t)bh * NC + c) * 4096;
        for (int idx = tid; idx < 4096; idx += 256)
            Scbuf[base + idx] = S_lds[(idx >> 6) * 65 + (idx & 63)];
        for (int idx = tid; idx < 4096; idx += 256) {
            P_lds[idx] = Pbuf[base + idx];
            U_lds[(idx >> 6) * 65 + (idx & 63)] = Ubuf[base + idx];
        }
        __syncthreads();
        float acc[16];
        #pragma unroll
        for (int jj = 0; jj < 16; ++jj) acc[jj] = 0.0f;
        for (int kx = 0; kx < 64; ++kx) {
            const float s = S_lds[i * 65 + kx];
            const f4* Prow = (const f4*)&P_lds[kx * 64 + jbase];
            const f4 p0 = Prow[0], p1 = Prow[1], p2 = Prow[2], p3 = Prow[3];
            acc[0] += s * p0.x; acc[1] += s * p0.y; acc[2] += s * p0.z; acc[3] += s * p0.w;
            acc[4] += s * p1.x; acc[5] += s * p1.y; acc[6] += s * p1.z; acc[7] += s * p1.w;
            acc[8] += s * p2.x; acc[9] += s * p2.y; acc[10] += s * p2.z; acc[11] += s * p2.w;
            acc[12] += s * p3.x; acc[13] += s * p3.y; acc[14] += s * p3.z; acc[15] += s * p3.w;
        }
        __syncthreads();
        #pragma unroll
        for (int jj = 0; jj < 16; ++jj)
            S_lds[i * 65 + jbase + jj] = acc[jj] + U_lds[i * 65 + jbase + jj];
        __syncthreads();
    }
}

// Phase C: per (b,h,chunk): exact recurrence from S_c, emit outputs. Named-reg state.
__global__ __launch_bounds__(64, 1) void chunk_out(
    const float* __restrict__ r, const float* __restrict__ w,
    const float* __restrict__ k, const float* __restrict__ v,
    const float* __restrict__ kk, const float* __restrict__ a,
    const float* __restrict__ Scbuf, float* __restrict__ o)
{
    const int bid = blockIdx.x;
    const int c = bid & (NC - 1);
    const int bh = bid >> 5;
    const int b = bh >> 4, h = bh & (NH_ - 1);
    const int lane = threadIdx.x;
    __shared__ __align__(16) float ew_s[64], ah_s[64], bh_s[64], kh_s[64], rh_s[64];

#define DECL_S(i) f4 s##i;
    REP16(DECL_S)
#undef DECL_S
    const f4* Srow = (const f4*)(Scbuf + (((size_t)bh * NC + c) * 64 + lane) * 64);
#define LD_S(i) s##i = Srow[i];
    REP16(LD_S)
#undef LD_S

    size_t idx = (((size_t)b * T_ + (size_t)c * CL) * NH_ + h) * 64 + lane;
    float wv = w[idx], kkv = kk[idx], av = a[idx], kv = k[idx], rv = r[idx], vv = v[idx];

    for (int t = 0; t < CL; ++t) {
        ew_s[lane] = expf(wv);
        ah_s[lane] = -kkv;
        bh_s[lane] = kkv * av;
        kh_s[lane] = kv;
        rh_s[lane] = rv;
        const float vcur = vv;
        const size_t oidx = idx;
        __syncthreads();
        if (t + 1 < CL) {
            idx += NH_ * 64;
            wv = w[idx]; kkv = kk[idx]; av = a[idx]; kv = k[idx]; rv = r[idx]; vv = v[idx];
        }
        const f4* A4 = (const f4*)ah_s;
        f4 ua = f4splat(0.0f);
#define DOTS_(i) { ua += s##i * A4[i]; }
        REP16(DOTS_)
#undef DOTS_
        const float sa = (ua.x + ua.y) + (ua.z + ua.w);
        const f4* E4 = (const f4*)ew_s;
        const f4* B4 = (const f4*)bh_s;
        const f4* K4 = (const f4*)kh_s;
        const f4* R4 = (const f4*)rh_s;
        f4 oa = f4splat(0.0f);
#define UPDO_(i) { f4 e = E4[i], bb = B4[i], kq = K4[i], rv4 = R4[i]; \
        s##i = s##i * e + sa * bb + vcur * kq; oa += s##i * rv4; }
        REP16(UPDO_)
#undef UPDO_
        o[oidx] = (oa.x + oa.y) + (oa.z + oa.w);
        __syncthreads();
    }
}

// GroupNorm(64) + r_k readout + output gate -> og
__global__ __launch_bounds__(256) void postproc(
    const float* __restrict__ o, const float* __restrict__ r, const float* __restrict__ k,
    const float* __restrict__ v, const float* __restrict__ g, const float* __restrict__ r_k,
    const float* __restrict__ gn_w, const float* __restrict__ gn_b,
    float* __restrict__ og)
{
    const int gid = blockIdx.x * 256 + threadIdx.x;
    const int i = gid & 63;
    const int h = (gid >> 6) & (NH_ - 1);
    const int ch = h * 64 + i;
    const float ov = o[gid];
    float s1 = ov, s2 = ov * ov;
    float term = r[gid] * k[gid] * r_k[ch];
    #pragma unroll
    for (int m = 32; m; m >>= 1) {
        s1 += __shfl_xor(s1, m, 64);
        s2 += __shfl_xor(s2, m, 64);
        term += __shfl_xor(term, m, 64);
    }
    const float mu = s1 * (1.0f / 64.0f);
    const float var = s2 * (1.0f / 64.0f) - mu * mu;
    const float on = (ov - mu) * rsqrtf(var + 6.4e-4f);
    const float outv = on * gn_w[ch] + gn_b[ch] + term * v[gid];
    og[gid] = outv * g[gid];
}

extern "C" void kernel_launch(void* const* d_in, const int* in_sizes, int n_in,
                              void* d_out, int out_size, void* d_ws, size_t ws_size,
                              hipStream_t stream)
{
    const float* hs      = (const float*)d_in[0];
    const float* context = (const float*)d_in[1];
    const float* v_first = (const float*)d_in[2];
    const float* x_r = (const float*)d_in[3];
    const float* x_w = (const float*)d_in[4];
    const float* x_k = (const float*)d_in[5];
    const float* x_v = (const float*)d_in[6];
    const float* x_a = (const float*)d_in[7];
    const float* x_g = (const float*)d_in[8];
    const float* k_k = (const float*)d_in[9];
    const float* k_a = (const float*)d_in[10];
    const float* r_k = (const float*)d_in[11];
    const float* W_r = (const float*)d_in[12];
    const float* W_k = (const float*)d_in[13];
    const float* W_v = (const float*)d_in[14];
    const float* W_o = (const float*)d_in[15];
    const float* W_cond = (const float*)d_in[16];
    const float* wA = (const float*)d_in[17];
    const float* wB = (const float*)d_in[18];
    const float* wb = (const float*)d_in[19];
    const float* aA = (const float*)d_in[20];
    const float* aB = (const float*)d_in[21];
    const float* ab = (const float*)d_in[22];
    const float* gA = (const float*)d_in[23];
    const float* gB = (const float*)d_in[24];
    const float* vA = (const float*)d_in[25];
    const float* vB = (const float*)d_in[26];
    const float* vb = (const float*)d_in[27];
    const float* gn_w = (const float*)d_in[28];
    const float* gn_b = (const float*)d_in[29];
    (void)in_sizes; (void)n_in; (void)out_size; (void)ws_size;

    // ---- workspace layout (floats), heavy aliasing ----
    float* ws = (float*)d_ws;
    float* cp    = ws;                  // [1024,1024]
    float* rbuf  = cp    + 1048576;     // [4096,1024]
    float* kbuf  = rbuf  + 4194304;
    float* vtmp  = kbuf  + 4194304;     // raw v; later Ubuf
    float* wbuf  = vtmp  + 4194304;     // log-decay w; later og
    float* abuf  = wbuf  + 4194304;
    float* obuf  = abuf  + 4194304;     // alias xr
    float* Pbuf  = obuf  + 4194304;     // alias xw
    float* Scbuf = Pbuf  + 4194304;     // alias xa
    float* kkbuf = Scbuf + 4194304;     // alias xg
    float* gbuf  = kkbuf + 4194304;     // alias xk
    float* vbuf  = gbuf  + 4194304;     // alias xv
    float* w1b   = vbuf  + 4194304;     // [4096,64]
    float* a1b   = w1b   + 262144;      // [4096,64]
    float* g1b   = a1b   + 262144;      // [4096,128]
    float* v1b   = g1b   + 524288;      // [4096,16]
    float* xr = obuf, *xw = Pbuf, *xa = Scbuf, *xg = kkbuf, *xk = gbuf, *xv = vbuf;
    float* Ubuf = vtmp;
    float* og   = wbuf;

    // u16 region: pre-transposed/split weights [N][K] hi,lo
    unsigned short* u = (unsigned short*)(v1b + 65536);
    unsigned short* condT_h = u;            u += 786432;
    unsigned short* condT_l = u;            u += 786432;
    unsigned short* rT_h = u;               u += 1048576;
    unsigned short* rT_l = u;               u += 1048576;
    unsigned short* kT_h = u;               u += 1048576;
    unsigned short* kT_l = u;               u += 1048576;
    unsigned short* vT_h = u;               u += 1048576;
    unsigned short* vT_l = u;               u += 1048576;
    unsigned short* oT_h = u;               u += 1048576;
    unsigned short* oT_l = u;               u += 1048576;
    unsigned short* waT_h = u;              u += 65536;
    unsigned short* waT_l = u;              u += 65536;
    unsigned short* wbT_h = u;              u += 65536;
    unsigned short* wbT_l = u;              u += 65536;
    unsigned short* aaT_h = u;              u += 65536;
    unsigned short* aaT_l = u;              u += 65536;
    unsigned short* abT_h = u;              u += 65536;
    unsigned short* abT_l = u;              u += 65536;
    unsigned short* gaT_h = u;              u += 131072;
    unsigned short* gaT_l = u;              u += 131072;
    unsigned short* gbT_h = u;              u += 131072;
    unsigned short* gbT_l = u;              u += 131072;
    unsigned short* vaT_h = u;              u += 16384;
    unsigned short* vaT_l = u;              u += 16384;
    unsigned short* vbT_h = u;              u += 16384;
    unsigned short* vbT_l = u;              u += 16384;

    const dim3 blk(256);
    // ---- weight transposes + bf16 hi/lo split ----
    wtrans<<<dim3(24, 32), blk, 0, stream>>>(W_cond, condT_h, condT_l, 768, 1024);
    wtrans<<<dim3(32, 32), blk, 0, stream>>>(W_r, rT_h, rT_l, 1024, 1024);
    wtrans<<<dim3(32, 32), blk, 0, stream>>>(W_k, kT_h, kT_l, 1024, 1024);
    wtrans<<<dim3(32, 32), blk, 0, stream>>>(W_v, vT_h, vT_l, 1024, 1024);
    wtrans<<<dim3(32, 32), blk, 0, stream>>>(W_o, oT_h, oT_l, 1024, 1024);
    wtrans<<<dim3(32, 2),  blk, 0, stream>>>(wA, waT_h, waT_l, 1024, 64);
    wtrans<<<dim3(2, 32),  blk, 0, stream>>>(wB, wbT_h, wbT_l, 64, 1024);
    wtrans<<<dim3(32, 2),  blk, 0, stream>>>(aA, aaT_h, aaT_l, 1024, 64);
    wtrans<<<dim3(2, 32),  blk, 0, stream>>>(aB, abT_h, abT_l, 64, 1024);
    wtrans<<<dim3(32, 4),  blk, 0, stream>>>(gA, gaT_h, gaT_l, 1024, 128);
    wtrans<<<dim3(4, 32),  blk, 0, stream>>>(gB, gbT_h, gbT_l, 128, 1024);
    wtrans<<<dim3(32, 1),  blk, 0, stream>>>(vA, vaT_h, vaT_l, 1024, 16);
    wtrans<<<dim3(1, 32),  blk, 0, stream>>>(vB, vbT_h, vbT_l, 16, 1024);

    // ---- activations ----
    hs_lerp4<<<dim3(4096), blk, 0, stream>>>(hs, x_r, x_w, x_a, x_g, xr, xw, xa, xg);
    // ctx projection: [1024,768] @ W_cond
    mgemm<128, 0><<<dim3(8, 8), blk, 0, stream>>>(context, condT_h, condT_l, cp,
                                                  1024, 1024, 768, nullptr, nullptr, nullptr);
    ctx_lerp2<<<dim3(4096), blk, 0, stream>>>(cp, x_k, x_v, xk, xv);

    // ---- main projections ----
    mgemm<128, 0><<<dim3(32, 8), blk, 0, stream>>>(xr, rT_h, rT_l, rbuf, 4096, 1024, 1024, nullptr, nullptr, nullptr);
    mgemm<128, 0><<<dim3(32, 8), blk, 0, stream>>>(xk, kT_h, kT_l, kbuf, 4096, 1024, 1024, nullptr, nullptr, nullptr);
    mgemm<128, 0><<<dim3(32, 8), blk, 0, stream>>>(xv, vT_h, vT_l, vtmp, 4096, 1024, 1024, nullptr, nullptr, nullptr);
    // ---- LoRA stage 1 ----
    mgemm<64, 4><<<dim3(32, 1), blk, 0, stream>>>(xw, waT_h, waT_l, w1b, 4096, 64, 1024, nullptr, nullptr, nullptr);   // tanh
    mgemm<64, 0><<<dim3(32, 1), blk, 0, stream>>>(xa, aaT_h, aaT_l, a1b, 4096, 64, 1024, nullptr, nullptr, nullptr);
    mgemm<64, 5><<<dim3(32, 2), blk, 0, stream>>>(xg, gaT_h, gaT_l, g1b, 4096, 128, 1024, nullptr, nullptr, nullptr);  // sigmoid
    mgemm<64, 0><<<dim3(32, 1), blk, 0, stream>>>(xv, vaT_h, vaT_l, v1b, 4096, 16, 1024, nullptr, nullptr, nullptr);
    // ---- LoRA stage 2 ----
    mgemm<128, 1><<<dim3(32, 8), blk, 0, stream>>>(w1b, wbT_h, wbT_l, wbuf, 4096, 1024, 64, wb, nullptr, nullptr);
    mgemm<128, 2><<<dim3(32, 8), blk, 0, stream>>>(a1b, abT_h, abT_l, abuf, 4096, 1024, 64, ab, nullptr, nullptr);
    mgemm<128, 0><<<dim3(32, 8), blk, 0, stream>>>(g1b, gbT_h, gbT_l, gbuf, 4096, 1024, 128, nullptr, nullptr, nullptr);
    mgemm<128, 3><<<dim3(32, 8), blk, 0, stream>>>(v1b, vbT_h, vbT_l, vbuf, 4096, 1024, 16, vb, vtmp, v_first);

    // ---- recurrence ----
    prep_k<<<dim3(16384), blk, 0, stream>>>(kbuf, abuf, k_k, k_a, kkbuf);
    chunk_AU<<<dim3(1024), dim3(64), 0, stream>>>(wbuf, kbuf, vbuf, kkbuf, abuf, Pbuf, Ubuf);
    chunk_scan<<<dim3(32), blk, 0, stream>>>(Pbuf, Ubuf, Scbuf);
    chunk_out<<<dim3(1024), dim3(64), 0, stream>>>(rbuf, wbuf, kbuf, vbuf, kkbuf, abuf, Scbuf, obuf);

    // ---- epilogue ----
    postproc<<<dim3(16384), blk, 0, stream>>>(obuf, rbuf, kbuf, vbuf, gbuf, r_k, gn_w, gn_b, og);
    mgemm<128, 0><<<dim3(32, 8), blk, 0, stream>>>(og, oT_h, oT_l, (float*)d_out, 4096, 1024, 1024, nullptr, nullptr, nullptr);
}

// Round 6
// 856.187 us; speedup vs baseline: 5.8698x; 1.5598x over previous
//
#include <hip/hip_runtime.h>
#include <cstddef>
#include <cstdint>

#define T_ 2048
#define H_ 1024
#define NH_ 16
#define LCTX 512
#define NC 32     // number of chunks
#define CL 64     // chunk length (NC*CL == T_)

typedef __attribute__((ext_vector_type(4))) float f4;
typedef __attribute__((ext_vector_type(4))) unsigned short u16x4;
typedef __attribute__((ext_vector_type(8))) short bf16x8;
typedef __attribute__((ext_vector_type(4))) float f32x4;

#define REP16(X) X(0) X(1) X(2) X(3) X(4) X(5) X(6) X(7) X(8) X(9) X(10) X(11) X(12) X(13) X(14) X(15)

__device__ __forceinline__ float sgm(float x) { return 1.0f / (1.0f + expf(-x)); }
__device__ __forceinline__ f4 f4splat(float v) { f4 r; r.x = v; r.y = v; r.z = v; r.w = v; return r; }

__device__ __forceinline__ unsigned short f2bf(float x) {   // RNE (weights, one-time)
    unsigned u = __float_as_uint(x);
    u += 0x7FFFu + ((u >> 16) & 1u);
    return (unsigned short)(u >> 16);
}
__device__ __forceinline__ float bf2f(unsigned short h) {
    return __uint_as_float(((unsigned)h) << 16);
}

// truncation split: x ~= hi + lo, |err| <= 2^-16 |x|
__device__ __forceinline__ void split1(float x, unsigned short& h, unsigned short& l) {
    unsigned u = __float_as_uint(x);
    h = (unsigned short)(u >> 16);
    float r = x - __uint_as_float(u & 0xFFFF0000u);
    l = (unsigned short)(__float_as_uint(r) >> 16);
}
__device__ __forceinline__ void split4(f4 v, u16x4& h, u16x4& l) {
    unsigned short hh, ll;
    split1(v.x, hh, ll); h.x = hh; l.x = ll;
    split1(v.y, hh, ll); h.y = hh; l.y = ll;
    split1(v.z, hh, ll); h.z = hh; l.z = ll;
    split1(v.w, hh, ll); h.w = hh; l.w = ll;
}

// ---------------- weight transpose + RNE split to bf16 hi/lo ----------------
// W [K][N] fp32  ->  Th, Tl [N][K] bf16-bits
__global__ __launch_bounds__(256) void wtrans(
    const float* __restrict__ W, unsigned short* __restrict__ Th,
    unsigned short* __restrict__ Tl, int K, int N)
{
    __shared__ float tile[32][33];
    const int k0 = blockIdx.x * 32, n0 = blockIdx.y * 32;
    const int t = threadIdx.x;
    const int r = t >> 3, c4 = (t & 7) * 4;
    f4 v = f4splat(0.0f);
    if (k0 + r < K && n0 + c4 < N)
        v = *(const f4*)(W + (size_t)(k0 + r) * N + n0 + c4);
    tile[r][c4 + 0] = v.x; tile[r][c4 + 1] = v.y;
    tile[r][c4 + 2] = v.z; tile[r][c4 + 3] = v.w;
    __syncthreads();
    if (n0 + r < N && k0 + c4 < K) {
        float x0 = tile[c4 + 0][r], x1 = tile[c4 + 1][r];
        float x2 = tile[c4 + 2][r], x3 = tile[c4 + 3][r];
        u16x4 hv, lv;
        hv.x = f2bf(x0); lv.x = f2bf(x0 - bf2f(hv.x));
        hv.y = f2bf(x1); lv.y = f2bf(x1 - bf2f(hv.y));
        hv.z = f2bf(x2); lv.z = f2bf(x2 - bf2f(hv.z));
        hv.w = f2bf(x3); lv.w = f2bf(x3 - bf2f(hv.w));
        *(u16x4*)(Th + (size_t)(n0 + r) * K + k0 + c4) = hv;
        *(u16x4*)(Tl + (size_t)(n0 + r) * K + k0 + c4) = lv;
    }
}

// plain fp32 -> split pair (context)
__global__ __launch_bounds__(256) void fsplit(
    const float* __restrict__ X, unsigned short* __restrict__ H,
    unsigned short* __restrict__ L, int n4)
{
    const int gid = blockIdx.x * 256 + threadIdx.x;
    if (gid >= n4) return;
    f4 v = ((const f4*)X)[gid];
    u16x4 h, l; split4(v, h, l);
    ((u16x4*)H)[gid] = h; ((u16x4*)L)[gid] = l;
}

// ---------------- elementwise prep (outputs pre-split hi/lo bf16) ----------------
__global__ __launch_bounds__(256) void hs_lerp4(
    const float* __restrict__ hs,
    const float* __restrict__ x_r, const float* __restrict__ x_w,
    const float* __restrict__ x_a, const float* __restrict__ x_g,
    unsigned short* __restrict__ xr_h, unsigned short* __restrict__ xr_l,
    unsigned short* __restrict__ xw_h, unsigned short* __restrict__ xw_l,
    unsigned short* __restrict__ xa_h, unsigned short* __restrict__ xa_l,
    unsigned short* __restrict__ xg_h, unsigned short* __restrict__ xg_l)
{
    const int gid = blockIdx.x * 256 + threadIdx.x;   // 1,048,576 f4 chunks
    const int c4 = (gid & 255) * 4;
    const int row = gid >> 8;
    const int tt = row & (T_ - 1);
    const f4 cur = *(const f4*)(hs + (size_t)row * H_ + c4);
    f4 prev = f4splat(0.0f);
    if (tt) prev = *(const f4*)(hs + (size_t)(row - 1) * H_ + c4);
    const f4 d = prev - cur;
    u16x4 h, l;
    split4(cur + d * (*(const f4*)(x_r + c4)), h, l);
    ((u16x4*)xr_h)[gid] = h; ((u16x4*)xr_l)[gid] = l;
    split4(cur + d * (*(const f4*)(x_w + c4)), h, l);
    ((u16x4*)xw_h)[gid] = h; ((u16x4*)xw_l)[gid] = l;
    split4(cur + d * (*(const f4*)(x_a + c4)), h, l);
    ((u16x4*)xa_h)[gid] = h; ((u16x4*)xa_l)[gid] = l;
    split4(cur + d * (*(const f4*)(x_g + c4)), h, l);
    ((u16x4*)xg_h)[gid] = h; ((u16x4*)xg_l)[gid] = l;
}

__device__ __forceinline__ f4 ctx_sample(const float* __restrict__ cp, int b, int t, int c4) {
    const float scale = (float)(511.0 / 2047.0);
    float tf = (float)t * scale;
    int lo = (int)tf;
    float f = tf - (float)lo;
    int hi = lo + 1; if (hi > LCTX - 1) hi = LCTX - 1;
    f4 cl = *(const f4*)(cp + (size_t)(b * LCTX + lo) * 1024 + c4);
    f4 ch = *(const f4*)(cp + (size_t)(b * LCTX + hi) * 1024 + c4);
    return cl + (ch - cl) * f;
}

__global__ __launch_bounds__(256) void ctx_lerp2(
    const float* __restrict__ cp,
    const float* __restrict__ x_k, const float* __restrict__ x_v,
    unsigned short* __restrict__ xk_h, unsigned short* __restrict__ xk_l,
    unsigned short* __restrict__ xv_h, unsigned short* __restrict__ xv_l)
{
    const int gid = blockIdx.x * 256 + threadIdx.x;
    const int c4 = (gid & 255) * 4;
    const int row = gid >> 8;
    const int b = row >> 11;
    const int tt = row & (T_ - 1);
    const f4 cur = ctx_sample(cp, b, tt, c4);
    f4 prev = f4splat(0.0f);
    if (tt) prev = ctx_sample(cp, b, tt - 1, c4);
    const f4 d = prev - cur;
    u16x4 h, l;
    split4(cur + d * (*(const f4*)(x_k + c4)), h, l);
    ((u16x4*)xk_h)[gid] = h; ((u16x4*)xk_l)[gid] = l;
    split4(cur + d * (*(const f4*)(x_v + c4)), h, l);
    ((u16x4*)xv_h)[gid] = h; ((u16x4*)xv_l)[gid] = l;
}

// ---------------- MFMA GEMM: C = A @ B, BOTH pre-split bf16 hi/lo row-major [.][K] ----
// acc += Ah*Bh + Ah*Bl + Al*Bh.  Tile 128x64, 4 waves, 2 blocks/CU.
// EPI: 0 plain, 1 LOGW*sgm(x+b), 2 sgm(x+b), 3 v-lerp, 4 tanh, 5 sgm
// OSPLIT: 1 -> store hi/lo u16 pair instead of fp32
template <int EPI, int OSPLIT>
__global__ __launch_bounds__(256, 2) void mgemm(
    const unsigned short* __restrict__ ATh, const unsigned short* __restrict__ ATl,
    const unsigned short* __restrict__ BTh, const unsigned short* __restrict__ BTl,
    float* __restrict__ C, unsigned short* __restrict__ Ch, unsigned short* __restrict__ Cl,
    int M, int N, int K,
    const float* __restrict__ bias, const float* __restrict__ aux1,
    const float* __restrict__ aux2)
{
    __shared__ __align__(16) unsigned short Ah_[8][4][16][8];
    __shared__ __align__(16) unsigned short Al_[8][4][16][8];
    __shared__ __align__(16) unsigned short Bh_[4][4][16][8];
    __shared__ __align__(16) unsigned short Bl_[4][4][16][8];
    const int tid = threadIdx.x;
    const int lane = tid & 63;
    const int wave = tid >> 6;
    const int bm = blockIdx.x * 128;
    const int bn = blockIdx.y * 64;
    const int wm = (wave >> 1) * 64;
    const int wn = (wave & 1) * 32;
    const int g = lane >> 4, rr = lane & 15;

    f32x4 acc[4][2];
    #pragma unroll
    for (int mi = 0; mi < 4; ++mi)
        #pragma unroll
        for (int ni = 0; ni < 2; ++ni)
            acc[mi][ni] = (f32x4)(0.0f);

    for (int k0 = 0; k0 < K; k0 += 32) {
        // ---- stage A tile 128x32 (pure copy, fragment order) ----
        #pragma unroll
        for (int it = 0; it < 4; ++it) {
            const int idx = tid + it * 256;
            const int row = idx >> 3;
            const int kt = (idx & 7) * 4;
            const int gk = k0 + kt;
            u16x4 hv, lv;
            hv.x = hv.y = hv.z = hv.w = 0;
            lv.x = lv.y = lv.z = lv.w = 0;
            if (gk < K) {
                hv = *(const u16x4*)(ATh + (size_t)(bm + row) * K + gk);
                lv = *(const u16x4*)(ATl + (size_t)(bm + row) * K + gk);
            }
            const int gg = (kt >> 2) & 3, e0 = (kt >> 4) * 4;
            *(u16x4*)&Ah_[row >> 4][gg][row & 15][e0] = hv;
            *(u16x4*)&Al_[row >> 4][gg][row & 15][e0] = lv;
        }
        // ---- stage B tile 64x32 ----
        #pragma unroll
        for (int it = 0; it < 2; ++it) {
            const int idx = tid + it * 256;
            const int row = idx >> 3;
            const int kt = (idx & 7) * 4;
            const int gk = k0 + kt;
            const int gn = bn + row;
            u16x4 hv, lv;
            hv.x = hv.y = hv.z = hv.w = 0;
            lv.x = lv.y = lv.z = lv.w = 0;
            if (gn < N && gk < K) {
                hv = *(const u16x4*)(BTh + (size_t)gn * K + gk);
                lv = *(const u16x4*)(BTl + (size_t)gn * K + gk);
            }
            const int gg = (kt >> 2) & 3, e0 = (kt >> 4) * 4;
            *(u16x4*)&Bh_[row >> 4][gg][row & 15][e0] = hv;
            *(u16x4*)&Bl_[row >> 4][gg][row & 15][e0] = lv;
        }
        __syncthreads();
        bf16x8 a_h[4], a_l[4], b_h[2], b_l[2];
        #pragma unroll
        for (int mi = 0; mi < 4; ++mi) {
            a_h[mi] = *(const bf16x8*)&Ah_[(wave >> 1) * 4 + mi][g][rr][0];
            a_l[mi] = *(const bf16x8*)&Al_[(wave >> 1) * 4 + mi][g][rr][0];
        }
        #pragma unroll
        for (int ni = 0; ni < 2; ++ni) {
            b_h[ni] = *(const bf16x8*)&Bh_[(wave & 1) * 2 + ni][g][rr][0];
            b_l[ni] = *(const bf16x8*)&Bl_[(wave & 1) * 2 + ni][g][rr][0];
        }
        #pragma unroll
        for (int mi = 0; mi < 4; ++mi)
            #pragma unroll
            for (int ni = 0; ni < 2; ++ni) {
                acc[mi][ni] = __builtin_amdgcn_mfma_f32_16x16x32_bf16(a_h[mi], b_h[ni], acc[mi][ni], 0, 0, 0);
                acc[mi][ni] = __builtin_amdgcn_mfma_f32_16x16x32_bf16(a_h[mi], b_l[ni], acc[mi][ni], 0, 0, 0);
                acc[mi][ni] = __builtin_amdgcn_mfma_f32_16x16x32_bf16(a_l[mi], b_h[ni], acc[mi][ni], 0, 0, 0);
            }
        __syncthreads();
    }
    // ---- epilogue: C row = (lane>>4)*4 + q, col = lane&15 (m89-verified) ----
    #pragma unroll
    for (int mi = 0; mi < 4; ++mi)
        #pragma unroll
        for (int ni = 0; ni < 2; ++ni)
            #pragma unroll
            for (int q = 0; q < 4; ++q) {
                const int grow = bm + wm + mi * 16 + g * 4 + q;
                const int gcol = bn + wn + ni * 16 + rr;
                if (gcol < N) {
                    const size_t o = (size_t)grow * N + gcol;
                    float x = acc[mi][ni][q];
                    if (EPI == 1) x = -0.6065306597126334f * sgm(x + bias[gcol]);
                    else if (EPI == 2) x = sgm(x + bias[gcol]);
                    else if (EPI == 3) {
                        float vt = aux1[o];
                        x = vt + sgm(x + bias[gcol]) * (aux2[o] - vt);
                    }
                    else if (EPI == 4) x = tanhf(x);
                    else if (EPI == 5) x = sgm(x);
                    if (OSPLIT) {
                        unsigned short hh, ll;
                        split1(x, hh, ll);
                        Ch[o] = hh; Cl[o] = ll;
                    } else {
                        C[o] = x;
                    }
                }
            }
}

// kk = normalize_per_head(k * k_k); k <- k * (1 + (a-1)*k_a)   (in place)
__global__ __launch_bounds__(256) void prep_k(
    float* __restrict__ k, const float* __restrict__ a,
    const float* __restrict__ k_k, const float* __restrict__ k_a,
    float* __restrict__ kk)
{
    const int gid = blockIdx.x * 256 + threadIdx.x;
    const int j = gid & 63;
    const int h = (gid >> 6) & (NH_ - 1);
    const int ch = h * 64 + j;
    const float kv = k[gid];
    float kkv = kv * k_k[ch];
    float ss = kkv * kkv;
    #pragma unroll
    for (int m = 32; m; m >>= 1) ss += __shfl_xor(ss, m, 64);
    const float nrm = fmaxf(sqrtf(ss), 1e-12f);
    kk[gid] = kkv / nrm;
    const float av = a[gid];
    k[gid] = kv * (1.0f + (av - 1.0f) * k_a[ch]);
}

// ---------------- Chunked RWKV7 scan ----------------
// Phase A: per (b,h,chunk): P_c = prod M_t (from I), U_c = chunk contribution from 0.
__global__ __launch_bounds__(64, 1) void chunk_AU(
    const float* __restrict__ w, const float* __restrict__ k,
    const float* __restrict__ v, const float* __restrict__ kk,
    const float* __restrict__ a,
    float* __restrict__ Pbuf, float* __restrict__ Ubuf)
{
    const int bid = blockIdx.x;
    const int c = bid & (NC - 1);
    const int bh = bid >> 5;
    const int b = bh >> 4, h = bh & (NH_ - 1);
    const int lane = threadIdx.x;
    __shared__ __align__(16) float ew_s[64], ah_s[64], bh_s[64], kh_s[64];

#define DECL_QU(i) f4 q##i = f4splat(0.0f), u##i = f4splat(0.0f);
    REP16(DECL_QU)
#undef DECL_QU
#define INIT_Q(i) \
    if (lane == 4*i+0) q##i.x = 1.0f; \
    else if (lane == 4*i+1) q##i.y = 1.0f; \
    else if (lane == 4*i+2) q##i.z = 1.0f; \
    else if (lane == 4*i+3) q##i.w = 1.0f;
    REP16(INIT_Q)
#undef INIT_Q

    size_t idx = (((size_t)b * T_ + (size_t)c * CL) * NH_ + h) * 64 + lane;
    float wv = w[idx], kkv = kk[idx], av = a[idx], kv = k[idx], vv = v[idx];

    for (int t = 0; t < CL; ++t) {
        ew_s[lane] = expf(wv);
        ah_s[lane] = -kkv;
        bh_s[lane] = kkv * av;
        kh_s[lane] = kv;
        const float vcur = vv;
        __syncthreads();
        if (t + 1 < CL) {
            idx += NH_ * 64;
            wv = w[idx]; kkv = kk[idx]; av = a[idx]; kv = k[idx]; vv = v[idx];
        }
        const f4* A4 = (const f4*)ah_s;
        f4 qa = f4splat(0.0f), ua = f4splat(0.0f);
#define DOT_(i) { f4 t4 = A4[i]; qa += q##i * t4; ua += u##i * t4; }
        REP16(DOT_)
#undef DOT_
        const float Qa = (qa.x + qa.y) + (qa.z + qa.w);
        const float Sa = (ua.x + ua.y) + (ua.z + ua.w);
        const f4* E4 = (const f4*)ew_s;
        const f4* B4 = (const f4*)bh_s;
        const f4* K4 = (const f4*)kh_s;
#define UPD_(i) { f4 e = E4[i], bb = B4[i], kq = K4[i]; \
        q##i = q##i * e + Qa * bb; \
        u##i = u##i * e + Sa * bb + vcur * kq; }
        REP16(UPD_)
#undef UPD_
        __syncthreads();
    }
    float* Pd = Pbuf + (((size_t)bh * NC + c) * 64 + lane) * 64;
    float* Ud = Ubuf + (((size_t)bh * NC + c) * 64 + lane) * 64;
#define ST_(i) ((f4*)Pd)[i] = q##i; ((f4*)Ud)[i] = u##i;
    REP16(ST_)
#undef ST_
}

// Phase B: row-parallel chunk scan. S rows are independent:
// s_new[j] = sum_k s[k]*P[k][j] + u[j].  128 blocks = 32 bh x 4 rowgroups;
// wave owns 4 rows; P staged in LDS (prefetched); s broadcast via b128 LDS read.
__global__ __launch_bounds__(256) void chunk_scan(
    const float* __restrict__ Pbuf, const float* __restrict__ Ubuf,
    float* __restrict__ Scbuf)
{
    const int blk = blockIdx.x;
    const int bh = blk >> 2;
    const int rg = blk & 3;
    const int tid = threadIdx.x;
    const int w = tid >> 6, j = tid & 63;
    const int r0 = rg * 16 + w * 4;
    __shared__ __align__(16) float P_lds[64 * 64];   // 16 KB
    __shared__ __align__(16) f4 s4_lds[4][64];       // 4 KB

    float a0 = 0, a1 = 0, a2 = 0, a3 = 0;
    // prefetch + write P for c=0
    {
        const float* Pb = Pbuf + ((size_t)bh * NC + 0) * 4096 + tid * 16;
        #pragma unroll
        for (int i = 0; i < 4; ++i)
            *(f4*)&P_lds[tid * 16 + i * 4] = *(const f4*)(Pb + i * 4);
    }
    for (int c = 0; c < NC; ++c) {
        // publish current state for broadcast
        f4 sv; sv.x = a0; sv.y = a1; sv.z = a2; sv.w = a3;
        s4_lds[w][j] = sv;
        // store chunk-start state
        {
            float* Sb = Scbuf + ((size_t)bh * NC + c) * 4096 + r0 * 64 + j;
            Sb[0] = a0; Sb[64] = a1; Sb[128] = a2; Sb[192] = a3;
        }
        // load U
        const float* Ub = Ubuf + ((size_t)bh * NC + c) * 4096 + r0 * 64 + j;
        float n0 = Ub[0], n1 = Ub[64], n2 = Ub[128], n3 = Ub[192];
        // prefetch next P into regs (hidden under inner loop)
        f4 pf0, pf1, pf2, pf3;
        if (c + 1 < NC) {
            const float* Pb = Pbuf + ((size_t)bh * NC + c + 1) * 4096 + tid * 16;
            pf0 = *(const f4*)(Pb + 0); pf1 = *(const f4*)(Pb + 4);
            pf2 = *(const f4*)(Pb + 8); pf3 = *(const f4*)(Pb + 12);
        }
        __syncthreads();
        #pragma unroll 8
        for (int k = 0; k < 64; ++k) {
            const f4 s = s4_lds[w][k];
            const float pv = P_lds[k * 64 + j];
            n0 += s.x * pv; n1 += s.y * pv; n2 += s.z * pv; n3 += s.w * pv;
        }
        a0 = n0; a1 = n1; a2 = n2; a3 = n3;
        __syncthreads();
        if (c + 1 < NC) {
            *(f4*)&P_lds[tid * 16 + 0]  = pf0;
            *(f4*)&P_lds[tid * 16 + 4]  = pf1;
            *(f4*)&P_lds[tid * 16 + 8]  = pf2;
            *(f4*)&P_lds[tid * 16 + 12] = pf3;
        }
    }
}

// Phase C: per (b,h,chunk): exact recurrence from S_c, emit outputs. Named-reg state.
__global__ __launch_bounds__(64, 1) void chunk_out(
    const float* __restrict__ r, const float* __restrict__ w,
    const float* __restrict__ k, const float* __restrict__ v,
    const float* __restrict__ kk, const float* __restrict__ a,
    const float* __restrict__ Scbuf, float* __restrict__ o)
{
    const int bid = blockIdx.x;
    const int c = bid & (NC - 1);
    const int bh = bid >> 5;
    const int b = bh >> 4, h = bh & (NH_ - 1);
    const int lane = threadIdx.x;
    __shared__ __align__(16) float ew_s[64], ah_s[64], bh_s[64], kh_s[64], rh_s[64];

#define DECL_S(i) f4 s##i;
    REP16(DECL_S)
#undef DECL_S
    const f4* Srow = (const f4*)(Scbuf + (((size_t)bh * NC + c) * 64 + lane) * 64);
#define LD_S(i) s##i = Srow[i];
    REP16(LD_S)
#undef LD_S

    size_t idx = (((size_t)b * T_ + (size_t)c * CL) * NH_ + h) * 64 + lane;
    float wv = w[idx], kkv = kk[idx], av = a[idx], kv = k[idx], rv = r[idx], vv = v[idx];

    for (int t = 0; t < CL; ++t) {
        ew_s[lane] = expf(wv);
        ah_s[lane] = -kkv;
        bh_s[lane] = kkv * av;
        kh_s[lane] = kv;
        rh_s[lane] = rv;
        const float vcur = vv;
        const size_t oidx = idx;
        __syncthreads();
        if (t + 1 < CL) {
            idx += NH_ * 64;
            wv = w[idx]; kkv = kk[idx]; av = a[idx]; kv = k[idx]; rv = r[idx]; vv = v[idx];
        }
        const f4* A4 = (const f4*)ah_s;
        f4 ua = f4splat(0.0f);
#define DOTS_(i) { ua += s##i * A4[i]; }
        REP16(DOTS_)
#undef DOTS_
        const float sa = (ua.x + ua.y) + (ua.z + ua.w);
        const f4* E4 = (const f4*)ew_s;
        const f4* B4 = (const f4*)bh_s;
        const f4* K4 = (const f4*)kh_s;
        const f4* R4 = (const f4*)rh_s;
        f4 oa = f4splat(0.0f);
#define UPDO_(i) { f4 e = E4[i], bb = B4[i], kq = K4[i], rv4 = R4[i]; \
        s##i = s##i * e + sa * bb + vcur * kq; oa += s##i * rv4; }
        REP16(UPDO_)
#undef UPDO_
        o[oidx] = (oa.x + oa.y) + (oa.z + oa.w);
        __syncthreads();
    }
}

// GroupNorm(64) + r_k readout + output gate -> og (pre-split pair)
__global__ __launch_bounds__(256) void postproc(
    const float* __restrict__ o, const float* __restrict__ r, const float* __restrict__ k,
    const float* __restrict__ v, const float* __restrict__ g, const float* __restrict__ r_k,
    const float* __restrict__ gn_w, const float* __restrict__ gn_b,
    unsigned short* __restrict__ og_h, unsigned short* __restrict__ og_l)
{
    const int gid = blockIdx.x * 256 + threadIdx.x;
    const int i = gid & 63;
    const int h = (gid >> 6) & (NH_ - 1);
    const int ch = h * 64 + i;
    const float ov = o[gid];
    float s1 = ov, s2 = ov * ov;
    float term = r[gid] * k[gid] * r_k[ch];
    #pragma unroll
    for (int m = 32; m; m >>= 1) {
        s1 += __shfl_xor(s1, m, 64);
        s2 += __shfl_xor(s2, m, 64);
        term += __shfl_xor(term, m, 64);
    }
    const float mu = s1 * (1.0f / 64.0f);
    const float var = s2 * (1.0f / 64.0f) - mu * mu;
    const float on = (ov - mu) * rsqrtf(var + 6.4e-4f);
    const float outv = (on * gn_w[ch] + gn_b[ch] + term * v[gid]) * g[gid];
    unsigned short hh, ll;
    split1(outv, hh, ll);
    og_h[gid] = hh; og_l[gid] = ll;
}

extern "C" void kernel_launch(void* const* d_in, const int* in_sizes, int n_in,
                              void* d_out, int out_size, void* d_ws, size_t ws_size,
                              hipStream_t stream)
{
    const float* hs      = (const float*)d_in[0];
    const float* context = (const float*)d_in[1];
    const float* v_first = (const float*)d_in[2];
    const float* x_r = (const float*)d_in[3];
    const float* x_w = (const float*)d_in[4];
    const float* x_k = (const float*)d_in[5];
    const float* x_v = (const float*)d_in[6];
    const float* x_a = (const float*)d_in[7];
    const float* x_g = (const float*)d_in[8];
    const float* k_k = (const float*)d_in[9];
    const float* k_a = (const float*)d_in[10];
    const float* r_k = (const float*)d_in[11];
    const float* W_r = (const float*)d_in[12];
    const float* W_k = (const float*)d_in[13];
    const float* W_v = (const float*)d_in[14];
    const float* W_o = (const float*)d_in[15];
    const float* W_cond = (const float*)d_in[16];
    const float* wA = (const float*)d_in[17];
    const float* wB = (const float*)d_in[18];
    const float* wb = (const float*)d_in[19];
    const float* aA = (const float*)d_in[20];
    const float* aB = (const float*)d_in[21];
    const float* ab = (const float*)d_in[22];
    const float* gA = (const float*)d_in[23];
    const float* gB = (const float*)d_in[24];
    const float* vA = (const float*)d_in[25];
    const float* vB = (const float*)d_in[26];
    const float* vb = (const float*)d_in[27];
    const float* gn_w = (const float*)d_in[28];
    const float* gn_b = (const float*)d_in[29];
    (void)in_sizes; (void)n_in; (void)out_size; (void)ws_size;

    // ---- workspace layout: 12 x 4M-float regions + 1M cp, activation pairs alias ----
    float* ws = (float*)d_ws;
    float* cp    = ws;                   // [1024,1024] f32
    float* rbuf  = cp    + (1 << 20);
    float* kbuf  = rbuf  + (4 << 20);
    float* vtmp  = kbuf  + (4 << 20);    // raw v; later Ubuf
    float* wbuf  = vtmp  + (4 << 20);    // log-decay w; later og pair
    float* abuf  = wbuf  + (4 << 20);
    float* obuf  = abuf  + (4 << 20);    // alias xr pair
    float* Pbuf  = obuf  + (4 << 20);    // alias xw pair
    float* Scbuf = Pbuf  + (4 << 20);    // alias xa pair
    float* kkbuf = Scbuf + (4 << 20);    // alias xk pair
    float* gbuf  = kkbuf + (4 << 20);    // alias xg pair
    float* vbuf  = gbuf  + (4 << 20);    // alias xv pair
    float* endf  = vbuf  + (4 << 20);
    float* Ubuf  = vtmp;

    unsigned short* xr_h = (unsigned short*)obuf;  unsigned short* xr_l = xr_h + (4 << 20);
    unsigned short* xw_h = (unsigned short*)Pbuf;  unsigned short* xw_l = xw_h + (4 << 20);
    unsigned short* xa_h = (unsigned short*)Scbuf; unsigned short* xa_l = xa_h + (4 << 20);
    unsigned short* xk_h = (unsigned short*)kkbuf; unsigned short* xk_l = xk_h + (4 << 20);
    unsigned short* xg_h = (unsigned short*)gbuf;  unsigned short* xg_l = xg_h + (4 << 20);
    unsigned short* xv_h = (unsigned short*)vbuf;  unsigned short* xv_l = xv_h + (4 << 20);
    unsigned short* og_h = (unsigned short*)wbuf;  unsigned short* og_l = og_h + (4 << 20);

    unsigned short* u = (unsigned short*)endf;
    unsigned short* ctx_h = u;  u += 786432;
    unsigned short* ctx_l = u;  u += 786432;
    unsigned short* w1h = u;    u += 262144;
    unsigned short* w1l = u;    u += 262144;
    unsigned short* a1h = u;    u += 262144;
    unsigned short* a1l = u;    u += 262144;
    unsigned short* g1h = u;    u += 524288;
    unsigned short* g1l = u;    u += 524288;
    unsigned short* v1h = u;    u += 65536;
    unsigned short* v1l = u;    u += 65536;
    unsigned short* condT_h = u; u += 786432;
    unsigned short* condT_l = u; u += 786432;
    unsigned short* rT_h = u;    u += 1048576;
    unsigned short* rT_l = u;    u += 1048576;
    unsigned short* kT_h = u;    u += 1048576;
    unsigned short* kT_l = u;    u += 1048576;
    unsigned short* vT_h = u;    u += 1048576;
    unsigned short* vT_l = u;    u += 1048576;
    unsigned short* oT_h = u;    u += 1048576;
    unsigned short* oT_l = u;    u += 1048576;
    unsigned short* waT_h = u;   u += 65536;
    unsigned short* waT_l = u;   u += 65536;
    unsigned short* wbT_h = u;   u += 65536;
    unsigned short* wbT_l = u;   u += 65536;
    unsigned short* aaT_h = u;   u += 65536;
    unsigned short* aaT_l = u;   u += 65536;
    unsigned short* abT_h = u;   u += 65536;
    unsigned short* abT_l = u;   u += 65536;
    unsigned short* gaT_h = u;   u += 131072;
    unsigned short* gaT_l = u;   u += 131072;
    unsigned short* gbT_h = u;   u += 131072;
    unsigned short* gbT_l = u;   u += 131072;
    unsigned short* vaT_h = u;   u += 16384;
    unsigned short* vaT_l = u;   u += 16384;
    unsigned short* vbT_h = u;   u += 16384;
    unsigned short* vbT_l = u;   u += 16384;

    const dim3 blk(256);
    // ---- weight transposes + RNE split ----
    wtrans<<<dim3(24, 32), blk, 0, stream>>>(W_cond, condT_h, condT_l, 768, 1024);
    wtrans<<<dim3(32, 32), blk, 0, stream>>>(W_r, rT_h, rT_l, 1024, 1024);
    wtrans<<<dim3(32, 32), blk, 0, stream>>>(W_k, kT_h, kT_l, 1024, 1024);
    wtrans<<<dim3(32, 32), blk, 0, stream>>>(W_v, vT_h, vT_l, 1024, 1024);
    wtrans<<<dim3(32, 32), blk, 0, stream>>>(W_o, oT_h, oT_l, 1024, 1024);
    wtrans<<<dim3(32, 2),  blk, 0, stream>>>(wA, waT_h, waT_l, 1024, 64);
    wtrans<<<dim3(2, 32),  blk, 0, stream>>>(wB, wbT_h, wbT_l, 64, 1024);
    wtrans<<<dim3(32, 2),  blk, 0, stream>>>(aA, aaT_h, aaT_l, 1024, 64);
    wtrans<<<dim3(2, 32),  blk, 0, stream>>>(aB, abT_h, abT_l, 64, 1024);
    wtrans<<<dim3(32, 4),  blk, 0, stream>>>(gA, gaT_h, gaT_l, 1024, 128);
    wtrans<<<dim3(4, 32),  blk, 0, stream>>>(gB, gbT_h, gbT_l, 128, 1024);
    wtrans<<<dim3(32, 1),  blk, 0, stream>>>(vA, vaT_h, vaT_l, 1024, 16);
    wtrans<<<dim3(1, 32),  blk, 0, stream>>>(vB, vbT_h, vbT_l, 16, 1024);

    // ---- activations (pre-split) ----
    fsplit<<<dim3(768), blk, 0, stream>>>(context, ctx_h, ctx_l, 196608);
    hs_lerp4<<<dim3(4096), blk, 0, stream>>>(hs, x_r, x_w, x_a, x_g,
                                             xr_h, xr_l, xw_h, xw_l, xa_h, xa_l, xg_h, xg_l);
    mgemm<0, 0><<<dim3(8, 16), blk, 0, stream>>>(ctx_h, ctx_l, condT_h, condT_l, cp,
                                                 nullptr, nullptr, 1024, 1024, 768,
                                                 nullptr, nullptr, nullptr);
    ctx_lerp2<<<dim3(4096), blk, 0, stream>>>(cp, x_k, x_v, xk_h, xk_l, xv_h, xv_l);

    // ---- main projections ----
    mgemm<0, 0><<<dim3(32, 16), blk, 0, stream>>>(xr_h, xr_l, rT_h, rT_l, rbuf, nullptr, nullptr,
                                                  4096, 1024, 1024, nullptr, nullptr, nullptr);
    mgemm<0, 0><<<dim3(32, 16), blk, 0, stream>>>(xk_h, xk_l, kT_h, kT_l, kbuf, nullptr, nullptr,
                                                  4096, 1024, 1024, nullptr, nullptr, nullptr);
    mgemm<0, 0><<<dim3(32, 16), blk, 0, stream>>>(xv_h, xv_l, vT_h, vT_l, vtmp, nullptr, nullptr,
                                                  4096, 1024, 1024, nullptr, nullptr, nullptr);
    // ---- LoRA stage 1 (split outputs) ----
    mgemm<4, 1><<<dim3(32, 1), blk, 0, stream>>>(xw_h, xw_l, waT_h, waT_l, nullptr, w1h, w1l,
                                                 4096, 64, 1024, nullptr, nullptr, nullptr);
    mgemm<0, 1><<<dim3(32, 1), blk, 0, stream>>>(xa_h, xa_l, aaT_h, aaT_l, nullptr, a1h, a1l,
                                                 4096, 64, 1024, nullptr, nullptr, nullptr);
    mgemm<5, 1><<<dim3(32, 2), blk, 0, stream>>>(xg_h, xg_l, gaT_h, gaT_l, nullptr, g1h, g1l,
                                                 4096, 128, 1024, nullptr, nullptr, nullptr);
    mgemm<0, 1><<<dim3(32, 1), blk, 0, stream>>>(xv_h, xv_l, vaT_h, vaT_l, nullptr, v1h, v1l,
                                                 4096, 16, 1024, nullptr, nullptr, nullptr);
    // ---- LoRA stage 2 ----
    mgemm<1, 0><<<dim3(32, 16), blk, 0, stream>>>(w1h, w1l, wbT_h, wbT_l, wbuf, nullptr, nullptr,
                                                  4096, 1024, 64, wb, nullptr, nullptr);
    mgemm<2, 0><<<dim3(32, 16), blk, 0, stream>>>(a1h, a1l, abT_h, abT_l, abuf, nullptr, nullptr,
                                                  4096, 1024, 64, ab, nullptr, nullptr);
    mgemm<0, 0><<<dim3(32, 16), blk, 0, stream>>>(g1h, g1l, gbT_h, gbT_l, gbuf, nullptr, nullptr,
                                                  4096, 1024, 128, nullptr, nullptr, nullptr);
    mgemm<3, 0><<<dim3(32, 16), blk, 0, stream>>>(v1h, v1l, vbT_h, vbT_l, vbuf, nullptr, nullptr,
                                                  4096, 1024, 16, vb, vtmp, v_first);

    // ---- recurrence ----
    prep_k<<<dim3(16384), blk, 0, stream>>>(kbuf, abuf, k_k, k_a, kkbuf);
    chunk_AU<<<dim3(1024), dim3(64), 0, stream>>>(wbuf, kbuf, vbuf, kkbuf, abuf, Pbuf, Ubuf);
    chunk_scan<<<dim3(128), blk, 0, stream>>>(Pbuf, Ubuf, Scbuf);
    chunk_out<<<dim3(1024), dim3(64), 0, stream>>>(rbuf, wbuf, kbuf, vbuf, kkbuf, abuf, Scbuf, obuf);

    // ---- epilogue ----
    postproc<<<dim3(16384), blk, 0, stream>>>(obuf, rbuf, kbuf, vbuf, gbuf, r_k, gn_w, gn_b, og_h, og_l);
    mgemm<0, 0><<<dim3(32, 16), blk, 0, stream>>>(og_h, og_l, oT_h, oT_l, (float*)d_out, nullptr, nullptr,
                                                  4096, 1024, 1024, nullptr, nullptr, nullptr);
}

// Round 7
// 769.958 us; speedup vs baseline: 6.5272x; 1.1120x over previous
//
#include <hip/hip_runtime.h>
#include <cstddef>
#include <cstdint>

#define T_ 2048
#define H_ 1024
#define NH_ 16
#define LCTX 512
#define NC 32     // number of chunks
#define CL 64     // chunk length (NC*CL == T_)

typedef __attribute__((ext_vector_type(4))) float f4;
typedef __attribute__((ext_vector_type(4))) unsigned short u16x4;
typedef __attribute__((ext_vector_type(8))) short bf16x8;
typedef __attribute__((ext_vector_type(4))) float f32x4;

#define REP16(X) X(0) X(1) X(2) X(3) X(4) X(5) X(6) X(7) X(8) X(9) X(10) X(11) X(12) X(13) X(14) X(15)
#define REP8(X) X(0) X(1) X(2) X(3) X(4) X(5) X(6) X(7)

__device__ __forceinline__ float sgm(float x) { return 1.0f / (1.0f + expf(-x)); }
__device__ __forceinline__ f4 f4splat(float v) { f4 r; r.x = v; r.y = v; r.z = v; r.w = v; return r; }
__device__ __forceinline__ float hsum4(f4 v) { return (v.x + v.y) + (v.z + v.w); }

__device__ __forceinline__ unsigned short f2bf(float x) {   // RNE (weights, one-time)
    unsigned u = __float_as_uint(x);
    u += 0x7FFFu + ((u >> 16) & 1u);
    return (unsigned short)(u >> 16);
}
__device__ __forceinline__ float bf2f(unsigned short h) {
    return __uint_as_float(((unsigned)h) << 16);
}

// truncation split: x ~= hi + lo, |err| <= 2^-16 |x|
__device__ __forceinline__ void split1(float x, unsigned short& h, unsigned short& l) {
    unsigned u = __float_as_uint(x);
    h = (unsigned short)(u >> 16);
    float r = x - __uint_as_float(u & 0xFFFF0000u);
    l = (unsigned short)(__float_as_uint(r) >> 16);
}
__device__ __forceinline__ void split4(f4 v, u16x4& h, u16x4& l) {
    unsigned short hh, ll;
    split1(v.x, hh, ll); h.x = hh; l.x = ll;
    split1(v.y, hh, ll); h.y = hh; l.y = ll;
    split1(v.z, hh, ll); h.z = hh; l.z = ll;
    split1(v.w, hh, ll); h.w = hh; l.w = ll;
}

// ---------------- fused weight transpose + RNE split (ALL weights, 1 launch) ----------------
struct WSeg { const float* W; unsigned short* Th; unsigned short* Tl; int K, N, tile0, tilesN; };
struct WAll { WSeg s[13]; };

__global__ __launch_bounds__(256) void wtrans_all(WAll all)
{
    const int bid = blockIdx.x;
    int si = 0;
    #pragma unroll
    for (int i = 1; i < 13; ++i) if (bid >= all.s[i].tile0) si = i;
    const WSeg sg = all.s[si];
    const int local = bid - sg.tile0;
    const int k0 = (local / sg.tilesN) * 32;
    const int n0 = (local % sg.tilesN) * 32;
    const int K = sg.K, N = sg.N;

    __shared__ float tile[32][33];
    const int t = threadIdx.x;
    const int r = t >> 3, c4 = (t & 7) * 4;
    f4 v = f4splat(0.0f);
    if (k0 + r < K && n0 + c4 < N)
        v = *(const f4*)(sg.W + (size_t)(k0 + r) * N + n0 + c4);
    tile[r][c4 + 0] = v.x; tile[r][c4 + 1] = v.y;
    tile[r][c4 + 2] = v.z; tile[r][c4 + 3] = v.w;
    __syncthreads();
    if (n0 + r < N && k0 + c4 < K) {
        float x0 = tile[c4 + 0][r], x1 = tile[c4 + 1][r];
        float x2 = tile[c4 + 2][r], x3 = tile[c4 + 3][r];
        u16x4 hv, lv;
        hv.x = f2bf(x0); lv.x = f2bf(x0 - bf2f(hv.x));
        hv.y = f2bf(x1); lv.y = f2bf(x1 - bf2f(hv.y));
        hv.z = f2bf(x2); lv.z = f2bf(x2 - bf2f(hv.z));
        hv.w = f2bf(x3); lv.w = f2bf(x3 - bf2f(hv.w));
        *(u16x4*)(sg.Th + (size_t)(n0 + r) * K + k0 + c4) = hv;
        *(u16x4*)(sg.Tl + (size_t)(n0 + r) * K + k0 + c4) = lv;
    }
}

// plain fp32 -> split pair (context)
__global__ __launch_bounds__(256) void fsplit(
    const float* __restrict__ X, unsigned short* __restrict__ H,
    unsigned short* __restrict__ L, int n4)
{
    const int gid = blockIdx.x * 256 + threadIdx.x;
    if (gid >= n4) return;
    f4 v = ((const f4*)X)[gid];
    u16x4 h, l; split4(v, h, l);
    ((u16x4*)H)[gid] = h; ((u16x4*)L)[gid] = l;
}

// ---------------- elementwise prep (outputs pre-split hi/lo bf16) ----------------
__global__ __launch_bounds__(256) void hs_lerp4(
    const float* __restrict__ hs,
    const float* __restrict__ x_r, const float* __restrict__ x_w,
    const float* __restrict__ x_a, const float* __restrict__ x_g,
    unsigned short* __restrict__ xr_h, unsigned short* __restrict__ xr_l,
    unsigned short* __restrict__ xw_h, unsigned short* __restrict__ xw_l,
    unsigned short* __restrict__ xa_h, unsigned short* __restrict__ xa_l,
    unsigned short* __restrict__ xg_h, unsigned short* __restrict__ xg_l)
{
    const int gid = blockIdx.x * 256 + threadIdx.x;   // 1,048,576 f4 chunks
    const int c4 = (gid & 255) * 4;
    const int row = gid >> 8;
    const int tt = row & (T_ - 1);
    const f4 cur = *(const f4*)(hs + (size_t)row * H_ + c4);
    f4 prev = f4splat(0.0f);
    if (tt) prev = *(const f4*)(hs + (size_t)(row - 1) * H_ + c4);
    const f4 d = prev - cur;
    u16x4 h, l;
    split4(cur + d * (*(const f4*)(x_r + c4)), h, l);
    ((u16x4*)xr_h)[gid] = h; ((u16x4*)xr_l)[gid] = l;
    split4(cur + d * (*(const f4*)(x_w + c4)), h, l);
    ((u16x4*)xw_h)[gid] = h; ((u16x4*)xw_l)[gid] = l;
    split4(cur + d * (*(const f4*)(x_a + c4)), h, l);
    ((u16x4*)xa_h)[gid] = h; ((u16x4*)xa_l)[gid] = l;
    split4(cur + d * (*(const f4*)(x_g + c4)), h, l);
    ((u16x4*)xg_h)[gid] = h; ((u16x4*)xg_l)[gid] = l;
}

__device__ __forceinline__ f4 ctx_sample(const float* __restrict__ cp, int b, int t, int c4) {
    const float scale = (float)(511.0 / 2047.0);
    float tf = (float)t * scale;
    int lo = (int)tf;
    float f = tf - (float)lo;
    int hi = lo + 1; if (hi > LCTX - 1) hi = LCTX - 1;
    f4 cl = *(const f4*)(cp + (size_t)(b * LCTX + lo) * 1024 + c4);
    f4 ch = *(const f4*)(cp + (size_t)(b * LCTX + hi) * 1024 + c4);
    return cl + (ch - cl) * f;
}

__global__ __launch_bounds__(256) void ctx_lerp2(
    const float* __restrict__ cp,
    const float* __restrict__ x_k, const float* __restrict__ x_v,
    unsigned short* __restrict__ xk_h, unsigned short* __restrict__ xk_l,
    unsigned short* __restrict__ xv_h, unsigned short* __restrict__ xv_l)
{
    const int gid = blockIdx.x * 256 + threadIdx.x;
    const int c4 = (gid & 255) * 4;
    const int row = gid >> 8;
    const int b = row >> 11;
    const int tt = row & (T_ - 1);
    const f4 cur = ctx_sample(cp, b, tt, c4);
    f4 prev = f4splat(0.0f);
    if (tt) prev = ctx_sample(cp, b, tt - 1, c4);
    const f4 d = prev - cur;
    u16x4 h, l;
    split4(cur + d * (*(const f4*)(x_k + c4)), h, l);
    ((u16x4*)xk_h)[gid] = h; ((u16x4*)xk_l)[gid] = l;
    split4(cur + d * (*(const f4*)(x_v + c4)), h, l);
    ((u16x4*)xv_h)[gid] = h; ((u16x4*)xv_l)[gid] = l;
}

// ---------------- MFMA GEMM: C = A @ B, BOTH pre-split bf16 hi/lo row-major [.][K] ----
// acc += Ah*Bh + Ah*Bl + Al*Bh.  Tile 128x64, 4 waves, 2 blocks/CU.
// EPI: 0 plain, 1 LOGW*sgm(x+b), 2 sgm(x+b), 3 v-lerp, 4 tanh, 5 sgm
// OSPLIT: 1 -> store hi/lo u16 pair instead of fp32
template <int EPI, int OSPLIT>
__global__ __launch_bounds__(256, 2) void mgemm(
    const unsigned short* __restrict__ ATh, const unsigned short* __restrict__ ATl,
    const unsigned short* __restrict__ BTh, const unsigned short* __restrict__ BTl,
    float* __restrict__ C, unsigned short* __restrict__ Ch, unsigned short* __restrict__ Cl,
    int M, int N, int K,
    const float* __restrict__ bias, const float* __restrict__ aux1,
    const float* __restrict__ aux2)
{
    __shared__ __align__(16) unsigned short Ah_[8][4][16][8];
    __shared__ __align__(16) unsigned short Al_[8][4][16][8];
    __shared__ __align__(16) unsigned short Bh_[4][4][16][8];
    __shared__ __align__(16) unsigned short Bl_[4][4][16][8];
    const int tid = threadIdx.x;
    const int lane = tid & 63;
    const int wave = tid >> 6;
    const int bm = blockIdx.x * 128;
    const int bn = blockIdx.y * 64;
    const int wm = (wave >> 1) * 64;
    const int wn = (wave & 1) * 32;
    const int g = lane >> 4, rr = lane & 15;

    f32x4 acc[4][2];
    #pragma unroll
    for (int mi = 0; mi < 4; ++mi)
        #pragma unroll
        for (int ni = 0; ni < 2; ++ni)
            acc[mi][ni] = (f32x4)(0.0f);

    for (int k0 = 0; k0 < K; k0 += 32) {
        // ---- stage A tile 128x32 (pure copy, fragment order) ----
        #pragma unroll
        for (int it = 0; it < 4; ++it) {
            const int idx = tid + it * 256;
            const int row = idx >> 3;
            const int kt = (idx & 7) * 4;
            const int gk = k0 + kt;
            u16x4 hv, lv;
            hv.x = hv.y = hv.z = hv.w = 0;
            lv.x = lv.y = lv.z = lv.w = 0;
            if (gk < K) {
                hv = *(const u16x4*)(ATh + (size_t)(bm + row) * K + gk);
                lv = *(const u16x4*)(ATl + (size_t)(bm + row) * K + gk);
            }
            const int gg = (kt >> 2) & 3, e0 = (kt >> 4) * 4;
            *(u16x4*)&Ah_[row >> 4][gg][row & 15][e0] = hv;
            *(u16x4*)&Al_[row >> 4][gg][row & 15][e0] = lv;
        }
        // ---- stage B tile 64x32 ----
        #pragma unroll
        for (int it = 0; it < 2; ++it) {
            const int idx = tid + it * 256;
            const int row = idx >> 3;
            const int kt = (idx & 7) * 4;
            const int gk = k0 + kt;
            const int gn = bn + row;
            u16x4 hv, lv;
            hv.x = hv.y = hv.z = hv.w = 0;
            lv.x = lv.y = lv.z = lv.w = 0;
            if (gn < N && gk < K) {
                hv = *(const u16x4*)(BTh + (size_t)gn * K + gk);
                lv = *(const u16x4*)(BTl + (size_t)gn * K + gk);
            }
            const int gg = (kt >> 2) & 3, e0 = (kt >> 4) * 4;
            *(u16x4*)&Bh_[row >> 4][gg][row & 15][e0] = hv;
            *(u16x4*)&Bl_[row >> 4][gg][row & 15][e0] = lv;
        }
        __syncthreads();
        bf16x8 a_h[4], a_l[4], b_h[2], b_l[2];
        #pragma unroll
        for (int mi = 0; mi < 4; ++mi) {
            a_h[mi] = *(const bf16x8*)&Ah_[(wave >> 1) * 4 + mi][g][rr][0];
            a_l[mi] = *(const bf16x8*)&Al_[(wave >> 1) * 4 + mi][g][rr][0];
        }
        #pragma unroll
        for (int ni = 0; ni < 2; ++ni) {
            b_h[ni] = *(const bf16x8*)&Bh_[(wave & 1) * 2 + ni][g][rr][0];
            b_l[ni] = *(const bf16x8*)&Bl_[(wave & 1) * 2 + ni][g][rr][0];
        }
        #pragma unroll
        for (int mi = 0; mi < 4; ++mi)
            #pragma unroll
            for (int ni = 0; ni < 2; ++ni) {
                acc[mi][ni] = __builtin_amdgcn_mfma_f32_16x16x32_bf16(a_h[mi], b_h[ni], acc[mi][ni], 0, 0, 0);
                acc[mi][ni] = __builtin_amdgcn_mfma_f32_16x16x32_bf16(a_h[mi], b_l[ni], acc[mi][ni], 0, 0, 0);
                acc[mi][ni] = __builtin_amdgcn_mfma_f32_16x16x32_bf16(a_l[mi], b_h[ni], acc[mi][ni], 0, 0, 0);
            }
        __syncthreads();
    }
    // ---- epilogue: C row = (lane>>4)*4 + q, col = lane&15 (m89-verified) ----
    #pragma unroll
    for (int mi = 0; mi < 4; ++mi)
        #pragma unroll
        for (int ni = 0; ni < 2; ++ni)
            #pragma unroll
            for (int q = 0; q < 4; ++q) {
                const int grow = bm + wm + mi * 16 + g * 4 + q;
                const int gcol = bn + wn + ni * 16 + rr;
                if (gcol < N) {
                    const size_t o = (size_t)grow * N + gcol;
                    float x = acc[mi][ni][q];
                    if (EPI == 1) x = -0.6065306597126334f * sgm(x + bias[gcol]);
                    else if (EPI == 2) x = sgm(x + bias[gcol]);
                    else if (EPI == 3) {
                        float vt = aux1[o];
                        x = vt + sgm(x + bias[gcol]) * (aux2[o] - vt);
                    }
                    else if (EPI == 4) x = tanhf(x);
                    else if (EPI == 5) x = sgm(x);
                    if (OSPLIT) {
                        unsigned short hh, ll;
                        split1(x, hh, ll);
                        Ch[o] = hh; Cl[o] = ll;
                    } else {
                        C[o] = x;
                    }
                }
            }
}

// kk = normalize_per_head(k * k_k); k <- k * (1 + (a-1)*k_a)   (in place)
__global__ __launch_bounds__(256) void prep_k(
    float* __restrict__ k, const float* __restrict__ a,
    const float* __restrict__ k_k, const float* __restrict__ k_a,
    float* __restrict__ kk)
{
    const int gid = blockIdx.x * 256 + threadIdx.x;
    const int j = gid & 63;
    const int h = (gid >> 6) & (NH_ - 1);
    const int ch = h * 64 + j;
    const float kv = k[gid];
    float kkv = kv * k_k[ch];
    float ss = kkv * kkv;
    #pragma unroll
    for (int m = 32; m; m >>= 1) ss += __shfl_xor(ss, m, 64);
    const float nrm = fmaxf(sqrtf(ss), 1e-12f);
    kk[gid] = kkv / nrm;
    const float av = a[gid];
    k[gid] = kv * (1.0f + (av - 1.0f) * k_a[ch]);
}

// ---------------- Chunked RWKV7 scan ----------------
// S_t = S_{t-1}(diag(e_t) + a_t b_t^T) + v_t k_t^T
// Phase A: 2 waves/block — wave0 evolves Q (=P product from I), wave1 evolves U (from 0).
// Both recurrences share the per-step LDS tiles; independent otherwise.
__global__ __launch_bounds__(128, 1) void chunk_AU(
    const float* __restrict__ w, const float* __restrict__ k,
    const float* __restrict__ v, const float* __restrict__ kk,
    const float* __restrict__ a,
    float* __restrict__ Pbuf, float* __restrict__ Ubuf)
{
    const int bid = blockIdx.x;
    const int c = bid & (NC - 1);
    const int bh = bid >> 5;
    const int b = bh >> 4, h = bh & (NH_ - 1);
    const int tid = threadIdx.x;
    const int wv_ = tid >> 6;        // 0 = Q-wave, 1 = U-wave
    const int lane = tid & 63;
    __shared__ __align__(16) float ew_s[64], ah_s[64], bh_s[64], kh_s[64];

#define DECL_X(i) f4 x##i = f4splat(0.0f);
    REP16(DECL_X)
#undef DECL_X
    if (wv_ == 0) {
        // identity row for lane
#define INIT_Q(i) \
        if (lane == 4*i+0) x##i.x = 1.0f; \
        else if (lane == 4*i+1) x##i.y = 1.0f; \
        else if (lane == 4*i+2) x##i.z = 1.0f; \
        else if (lane == 4*i+3) x##i.w = 1.0f;
        REP16(INIT_Q)
#undef INIT_Q
    }

    size_t idx = (((size_t)b * T_ + (size_t)c * CL) * NH_ + h) * 64 + lane;
    float wvv = 0, kkv = 0, av = 0, kv = 0, vvv = 0;
    if (wv_ == 0) { wvv = w[idx]; kkv = kk[idx]; av = a[idx]; }
    else          { kv = k[idx]; vvv = v[idx]; }

    for (int t = 0; t < CL; ++t) {
        if (wv_ == 0) {
            ew_s[lane] = expf(wvv);
            ah_s[lane] = -kkv;
            bh_s[lane] = kkv * av;
        } else {
            kh_s[lane] = kv;
        }
        const float vcur = vvv;
        __syncthreads();
        if (t + 1 < CL) {
            idx += NH_ * 64;
            if (wv_ == 0) { wvv = w[idx]; kkv = kk[idx]; av = a[idx]; }
            else          { kv = k[idx]; vvv = v[idx]; }
        }
        const f4* A4 = (const f4*)ah_s;
        f4 da = f4splat(0.0f);
#define DOT_(i) { da += x##i * A4[i]; }
        REP16(DOT_)
#undef DOT_
        const float Da = hsum4(da);
        const f4* E4 = (const f4*)ew_s;
        const f4* B4 = (const f4*)bh_s;
        if (wv_ == 0) {
#define UPDQ_(i) { x##i = x##i * E4[i] + Da * B4[i]; }
            REP16(UPDQ_)
#undef UPDQ_
        } else {
            const f4* K4 = (const f4*)kh_s;
#define UPDU_(i) { x##i = x##i * E4[i] + Da * B4[i] + vcur * K4[i]; }
            REP16(UPDU_)
#undef UPDU_
        }
        __syncthreads();
    }
    float* Dst = (wv_ == 0 ? Pbuf : Ubuf) + (((size_t)bh * NC + c) * 64 + lane) * 64;
#define ST_(i) ((f4*)Dst)[i] = x##i;
    REP16(ST_)
#undef ST_
}

// Phase B: row-parallel chunk scan. 128 blocks = 32 bh x 4 rowgroups;
// wave owns 4 rows; P staged in LDS (prefetched); s broadcast via b128 LDS read.
__global__ __launch_bounds__(256) void chunk_scan(
    const float* __restrict__ Pbuf, const float* __restrict__ Ubuf,
    float* __restrict__ Scbuf)
{
    const int blk = blockIdx.x;
    const int bh = blk >> 2;
    const int rg = blk & 3;
    const int tid = threadIdx.x;
    const int w = tid >> 6, j = tid & 63;
    const int r0 = rg * 16 + w * 4;
    __shared__ __align__(16) float P_lds[64 * 64];   // 16 KB
    __shared__ __align__(16) f4 s4_lds[4][64];       // 4 KB

    float a0 = 0, a1 = 0, a2 = 0, a3 = 0;
    {
        const float* Pb = Pbuf + ((size_t)bh * NC + 0) * 4096 + tid * 16;
        #pragma unroll
        for (int i = 0; i < 4; ++i)
            *(f4*)&P_lds[tid * 16 + i * 4] = *(const f4*)(Pb + i * 4);
    }
    for (int c = 0; c < NC; ++c) {
        f4 sv; sv.x = a0; sv.y = a1; sv.z = a2; sv.w = a3;
        s4_lds[w][j] = sv;
        {
            float* Sb = Scbuf + ((size_t)bh * NC + c) * 4096 + r0 * 64 + j;
            Sb[0] = a0; Sb[64] = a1; Sb[128] = a2; Sb[192] = a3;
        }
        const float* Ub = Ubuf + ((size_t)bh * NC + c) * 4096 + r0 * 64 + j;
        float n0 = Ub[0], n1 = Ub[64], n2 = Ub[128], n3 = Ub[192];
        f4 pf0, pf1, pf2, pf3;
        if (c + 1 < NC) {
            const float* Pb = Pbuf + ((size_t)bh * NC + c + 1) * 4096 + tid * 16;
            pf0 = *(const f4*)(Pb + 0); pf1 = *(const f4*)(Pb + 4);
            pf2 = *(const f4*)(Pb + 8); pf3 = *(const f4*)(Pb + 12);
        }
        __syncthreads();
        #pragma unroll 8
        for (int k = 0; k < 64; ++k) {
            const f4 s = s4_lds[w][k];
            const float pv = P_lds[k * 64 + j];
            n0 += s.x * pv; n1 += s.y * pv; n2 += s.z * pv; n3 += s.w * pv;
        }
        a0 = n0; a1 = n1; a2 = n2; a3 = n3;
        __syncthreads();
        if (c + 1 < NC) {
            *(f4*)&P_lds[tid * 16 + 0]  = pf0;
            *(f4*)&P_lds[tid * 16 + 4]  = pf1;
            *(f4*)&P_lds[tid * 16 + 8]  = pf2;
            *(f4*)&P_lds[tid * 16 + 12] = pf3;
        }
    }
}

// Phase C: 2 waves/block, state column-split (wave owns 32 cols). sa and o
// partials exchanged via LDS; o stored one step deferred by wave0.
__global__ __launch_bounds__(128, 1) void chunk_out(
    const float* __restrict__ r, const float* __restrict__ w,
    const float* __restrict__ k, const float* __restrict__ v,
    const float* __restrict__ kk, const float* __restrict__ a,
    const float* __restrict__ Scbuf, float* __restrict__ o)
{
    const int bid = blockIdx.x;
    const int c = bid & (NC - 1);
    const int bh = bid >> 5;
    const int b = bh >> 4, h = bh & (NH_ - 1);
    const int tid = threadIdx.x;
    const int wv_ = tid >> 6;
    const int lane = tid & 63;
    __shared__ __align__(16) float ew_s[64], ah_s[64], bh_s[64], kh_s[64], rh_s[64];
    __shared__ float sa_part[2][64];
    __shared__ float op_part[64];

#define DECL_S(i) f4 s##i;
    REP8(DECL_S)
#undef DECL_S
    const f4* Srow = (const f4*)(Scbuf + (((size_t)bh * NC + c) * 64 + lane) * 64 + wv_ * 32);
#define LD_S(i) s##i = Srow[i];
    REP8(LD_S)
#undef LD_S

    size_t idx = (((size_t)b * T_ + (size_t)c * CL) * NH_ + h) * 64 + lane;
    float wvv = 0, kkv = 0, av = 0, kv = 0, rv = 0, vvv;
    if (wv_ == 0) { wvv = w[idx]; kkv = kk[idx]; av = a[idx]; }
    else          { kv = k[idx]; rv = r[idx]; }
    vvv = v[idx];

    float oprev = 0.0f;
    size_t oprev_idx = 0;

    for (int t = 0; t < CL; ++t) {
        // deferred o store from previous step (reads op_part written pre-barrier3 of t-1)
        if (t > 0 && wv_ == 0) o[oprev_idx] = oprev + op_part[lane];
        if (wv_ == 0) {
            ew_s[lane] = expf(wvv);
            ah_s[lane] = -kkv;
            bh_s[lane] = kkv * av;
        } else {
            kh_s[lane] = kv;
            rh_s[lane] = rv;
        }
        const float vcur = vvv;
        const size_t oidx = idx;
        __syncthreads();                                   // barrier1: stage ready
        if (t + 1 < CL) {
            idx += NH_ * 64;
            if (wv_ == 0) { wvv = w[idx]; kkv = kk[idx]; av = a[idx]; }
            else          { kv = k[idx]; rv = r[idx]; }
            vvv = v[idx];
        }
        const f4* A4 = (const f4*)(ah_s + wv_ * 32);
        f4 ua = f4splat(0.0f);
#define DOTS_(i) { ua += s##i * A4[i]; }
        REP8(DOTS_)
#undef DOTS_
        sa_part[wv_][lane] = hsum4(ua);
        __syncthreads();                                   // barrier2: partials ready
        const float sa = sa_part[0][lane] + sa_part[1][lane];
        const f4* E4 = (const f4*)(ew_s + wv_ * 32);
        const f4* B4 = (const f4*)(bh_s + wv_ * 32);
        const f4* K4 = (const f4*)(kh_s + wv_ * 32);
        const f4* R4 = (const f4*)(rh_s + wv_ * 32);
        f4 oa = f4splat(0.0f);
#define UPDO_(i) { s##i = s##i * E4[i] + sa * B4[i] + vcur * K4[i]; oa += s##i * R4[i]; }
        REP8(UPDO_)
#undef UPDO_
        const float o_w = hsum4(oa);
        if (wv_ == 1) op_part[lane] = o_w;
        else { oprev = o_w; oprev_idx = oidx; }
        __syncthreads();                                   // barrier3: end of step
    }
    if (wv_ == 0) o[oprev_idx] = oprev + op_part[lane];
}

// GroupNorm(64) + r_k readout + output gate -> og (pre-split pair)
__global__ __launch_bounds__(256) void postproc(
    const float* __restrict__ o, const float* __restrict__ r, const float* __restrict__ k,
    const float* __restrict__ v, const float* __restrict__ g, const float* __restrict__ r_k,
    const float* __restrict__ gn_w, const float* __restrict__ gn_b,
    unsigned short* __restrict__ og_h, unsigned short* __restrict__ og_l)
{
    const int gid = blockIdx.x * 256 + threadIdx.x;
    const int i = gid & 63;
    const int h = (gid >> 6) & (NH_ - 1);
    const int ch = h * 64 + i;
    const float ov = o[gid];
    float s1 = ov, s2 = ov * ov;
    float term = r[gid] * k[gid] * r_k[ch];
    #pragma unroll
    for (int m = 32; m; m >>= 1) {
        s1 += __shfl_xor(s1, m, 64);
        s2 += __shfl_xor(s2, m, 64);
        term += __shfl_xor(term, m, 64);
    }
    const float mu = s1 * (1.0f / 64.0f);
    const float var = s2 * (1.0f / 64.0f) - mu * mu;
    const float on = (ov - mu) * rsqrtf(var + 6.4e-4f);
    const float outv = (on * gn_w[ch] + gn_b[ch] + term * v[gid]) * g[gid];
    unsigned short hh, ll;
    split1(outv, hh, ll);
    og_h[gid] = hh; og_l[gid] = ll;
}

extern "C" void kernel_launch(void* const* d_in, const int* in_sizes, int n_in,
                              void* d_out, int out_size, void* d_ws, size_t ws_size,
                              hipStream_t stream)
{
    const float* hs      = (const float*)d_in[0];
    const float* context = (const float*)d_in[1];
    const float* v_first = (const float*)d_in[2];
    const float* x_r = (const float*)d_in[3];
    const float* x_w = (const float*)d_in[4];
    const float* x_k = (const float*)d_in[5];
    const float* x_v = (const float*)d_in[6];
    const float* x_a = (const float*)d_in[7];
    const float* x_g = (const float*)d_in[8];
    const float* k_k = (const float*)d_in[9];
    const float* k_a = (const float*)d_in[10];
    const float* r_k = (const float*)d_in[11];
    const float* W_r = (const float*)d_in[12];
    const float* W_k = (const float*)d_in[13];
    const float* W_v = (const float*)d_in[14];
    const float* W_o = (const float*)d_in[15];
    const float* W_cond = (const float*)d_in[16];
    const float* wA = (const float*)d_in[17];
    const float* wB = (const float*)d_in[18];
    const float* wb = (const float*)d_in[19];
    const float* aA = (const float*)d_in[20];
    const float* aB = (const float*)d_in[21];
    const float* ab = (const float*)d_in[22];
    const float* gA = (const float*)d_in[23];
    const float* gB = (const float*)d_in[24];
    const float* vA = (const float*)d_in[25];
    const float* vB = (const float*)d_in[26];
    const float* vb = (const float*)d_in[27];
    const float* gn_w = (const float*)d_in[28];
    const float* gn_b = (const float*)d_in[29];
    (void)in_sizes; (void)n_in; (void)out_size; (void)ws_size;

    // ---- workspace layout: 12 x 4M-float regions + 1M cp, activation pairs alias ----
    float* ws = (float*)d_ws;
    float* cp    = ws;                   // [1024,1024] f32
    float* rbuf  = cp    + (1 << 20);
    float* kbuf  = rbuf  + (4 << 20);
    float* vtmp  = kbuf  + (4 << 20);    // raw v; later Ubuf
    float* wbuf  = vtmp  + (4 << 20);    // log-decay w; later og pair
    float* abuf  = wbuf  + (4 << 20);
    float* obuf  = abuf  + (4 << 20);    // alias xr pair
    float* Pbuf  = obuf  + (4 << 20);    // alias xw pair
    float* Scbuf = Pbuf  + (4 << 20);    // alias xa pair
    float* kkbuf = Scbuf + (4 << 20);    // alias xk pair
    float* gbuf  = kkbuf + (4 << 20);    // alias xg pair
    float* vbuf  = gbuf  + (4 << 20);    // alias xv pair
    float* endf  = vbuf  + (4 << 20);
    float* Ubuf  = vtmp;

    unsigned short* xr_h = (unsigned short*)obuf;  unsigned short* xr_l = xr_h + (4 << 20);
    unsigned short* xw_h = (unsigned short*)Pbuf;  unsigned short* xw_l = xw_h + (4 << 20);
    unsigned short* xa_h = (unsigned short*)Scbuf; unsigned short* xa_l = xa_h + (4 << 20);
    unsigned short* xk_h = (unsigned short*)kkbuf; unsigned short* xk_l = xk_h + (4 << 20);
    unsigned short* xg_h = (unsigned short*)gbuf;  unsigned short* xg_l = xg_h + (4 << 20);
    unsigned short* xv_h = (unsigned short*)vbuf;  unsigned short* xv_l = xv_h + (4 << 20);
    unsigned short* og_h = (unsigned short*)wbuf;  unsigned short* og_l = og_h + (4 << 20);

    unsigned short* u = (unsigned short*)endf;
    unsigned short* ctx_h = u;  u += 786432;
    unsigned short* ctx_l = u;  u += 786432;
    unsigned short* w1h = u;    u += 262144;
    unsigned short* w1l = u;    u += 262144;
    unsigned short* a1h = u;    u += 262144;
    unsigned short* a1l = u;    u += 262144;
    unsigned short* g1h = u;    u += 524288;
    unsigned short* g1l = u;    u += 524288;
    unsigned short* v1h = u;    u += 65536;
    unsigned short* v1l = u;    u += 65536;
    unsigned short* condT_h = u; u += 786432;
    unsigned short* condT_l = u; u += 786432;
    unsigned short* rT_h = u;    u += 1048576;
    unsigned short* rT_l = u;    u += 1048576;
    unsigned short* kT_h = u;    u += 1048576;
    unsigned short* kT_l = u;    u += 1048576;
    unsigned short* vT_h = u;    u += 1048576;
    unsigned short* vT_l = u;    u += 1048576;
    unsigned short* oT_h = u;    u += 1048576;
    unsigned short* oT_l = u;    u += 1048576;
    unsigned short* waT_h = u;   u += 65536;
    unsigned short* waT_l = u;   u += 65536;
    unsigned short* wbT_h = u;   u += 65536;
    unsigned short* wbT_l = u;   u += 65536;
    unsigned short* aaT_h = u;   u += 65536;
    unsigned short* aaT_l = u;   u += 65536;
    unsigned short* abT_h = u;   u += 65536;
    unsigned short* abT_l = u;   u += 65536;
    unsigned short* gaT_h = u;   u += 131072;
    unsigned short* gaT_l = u;   u += 131072;
    unsigned short* gbT_h = u;   u += 131072;
    unsigned short* gbT_l = u;   u += 131072;
    unsigned short* vaT_h = u;   u += 16384;
    unsigned short* vaT_l = u;   u += 16384;
    unsigned short* vbT_h = u;   u += 16384;
    unsigned short* vbT_l = u;   u += 16384;

    const dim3 blk(256);
    // ---- fused weight transposes + RNE split (1 launch) ----
    {
        WAll all;
        auto seg = [](const float* W, unsigned short* Th, unsigned short* Tl,
                      int K, int N, int tile0) {
            WSeg s; s.W = W; s.Th = Th; s.Tl = Tl; s.K = K; s.N = N;
            s.tile0 = tile0; s.tilesN = (N + 31) / 32; return s;
        };
        int t0 = 0;
        all.s[0]  = seg(W_cond, condT_h, condT_l, 768, 1024, t0);  t0 += 24 * 32;
        all.s[1]  = seg(W_r, rT_h, rT_l, 1024, 1024, t0);          t0 += 32 * 32;
        all.s[2]  = seg(W_k, kT_h, kT_l, 1024, 1024, t0);          t0 += 32 * 32;
        all.s[3]  = seg(W_v, vT_h, vT_l, 1024, 1024, t0);          t0 += 32 * 32;
        all.s[4]  = seg(W_o, oT_h, oT_l, 1024, 1024, t0);          t0 += 32 * 32;
        all.s[5]  = seg(wA, waT_h, waT_l, 1024, 64, t0);           t0 += 32 * 2;
        all.s[6]  = seg(wB, wbT_h, wbT_l, 64, 1024, t0);           t0 += 2 * 32;
        all.s[7]  = seg(aA, aaT_h, aaT_l, 1024, 64, t0);           t0 += 32 * 2;
        all.s[8]  = seg(aB, abT_h, abT_l, 64, 1024, t0);           t0 += 2 * 32;
        all.s[9]  = seg(gA, gaT_h, gaT_l, 1024, 128, t0);          t0 += 32 * 4;
        all.s[10] = seg(gB, gbT_h, gbT_l, 128, 1024, t0);          t0 += 4 * 32;
        all.s[11] = seg(vA, vaT_h, vaT_l, 1024, 16, t0);           t0 += 32 * 1;
        all.s[12] = seg(vB, vbT_h, vbT_l, 16, 1024, t0);           t0 += 1 * 32;
        wtrans_all<<<dim3(t0), blk, 0, stream>>>(all);
    }

    // ---- activations (pre-split) ----
    fsplit<<<dim3(768), blk, 0, stream>>>(context, ctx_h, ctx_l, 196608);
    hs_lerp4<<<dim3(4096), blk, 0, stream>>>(hs, x_r, x_w, x_a, x_g,
                                             xr_h, xr_l, xw_h, xw_l, xa_h, xa_l, xg_h, xg_l);
    mgemm<0, 0><<<dim3(8, 16), blk, 0, stream>>>(ctx_h, ctx_l, condT_h, condT_l, cp,
                                                 nullptr, nullptr, 1024, 1024, 768,
                                                 nullptr, nullptr, nullptr);
    ctx_lerp2<<<dim3(4096), blk, 0, stream>>>(cp, x_k, x_v, xk_h, xk_l, xv_h, xv_l);

    // ---- main projections ----
    mgemm<0, 0><<<dim3(32, 16), blk, 0, stream>>>(xr_h, xr_l, rT_h, rT_l, rbuf, nullptr, nullptr,
                                                  4096, 1024, 1024, nullptr, nullptr, nullptr);
    mgemm<0, 0><<<dim3(32, 16), blk, 0, stream>>>(xk_h, xk_l, kT_h, kT_l, kbuf, nullptr, nullptr,
                                                  4096, 1024, 1024, nullptr, nullptr, nullptr);
    mgemm<0, 0><<<dim3(32, 16), blk, 0, stream>>>(xv_h, xv_l, vT_h, vT_l, vtmp, nullptr, nullptr,
                                                  4096, 1024, 1024, nullptr, nullptr, nullptr);
    // ---- LoRA stage 1 (split outputs) ----
    mgemm<4, 1><<<dim3(32, 1), blk, 0, stream>>>(xw_h, xw_l, waT_h, waT_l, nullptr, w1h, w1l,
                                                 4096, 64, 1024, nullptr, nullptr, nullptr);
    mgemm<0, 1><<<dim3(32, 1), blk, 0, stream>>>(xa_h, xa_l, aaT_h, aaT_l, nullptr, a1h, a1l,
                                                 4096, 64, 1024, nullptr, nullptr, nullptr);
    mgemm<5, 1><<<dim3(32, 2), blk, 0, stream>>>(xg_h, xg_l, gaT_h, gaT_l, nullptr, g1h, g1l,
                                                 4096, 128, 1024, nullptr, nullptr, nullptr);
    mgemm<0, 1><<<dim3(32, 1), blk, 0, stream>>>(xv_h, xv_l, vaT_h, vaT_l, nullptr, v1h, v1l,
                                                 4096, 16, 1024, nullptr, nullptr, nullptr);
    // ---- LoRA stage 2 ----
    mgemm<1, 0><<<dim3(32, 16), blk, 0, stream>>>(w1h, w1l, wbT_h, wbT_l, wbuf, nullptr, nullptr,
                                                  4096, 1024, 64, wb, nullptr, nullptr);
    mgemm<2, 0><<<dim3(32, 16), blk, 0, stream>>>(a1h, a1l, abT_h, abT_l, abuf, nullptr, nullptr,
                                                  4096, 1024, 64, ab, nullptr, nullptr);
    mgemm<0, 0><<<dim3(32, 16), blk, 0, stream>>>(g1h, g1l, gbT_h, gbT_l, gbuf, nullptr, nullptr,
                                                  4096, 1024, 128, nullptr, nullptr, nullptr);
    mgemm<3, 0><<<dim3(32, 16), blk, 0, stream>>>(v1h, v1l, vbT_h, vbT_l, vbuf, nullptr, nullptr,
                                                  4096, 1024, 16, vb, vtmp, v_first);

    // ---- recurrence ----
    prep_k<<<dim3(16384), blk, 0, stream>>>(kbuf, abuf, k_k, k_a, kkbuf);
    chunk_AU<<<dim3(1024), dim3(128), 0, stream>>>(wbuf, kbuf, vbuf, kkbuf, abuf, Pbuf, Ubuf);
    chunk_scan<<<dim3(128), blk, 0, stream>>>(Pbuf, Ubuf, Scbuf);
    chunk_out<<<dim3(1024), dim3(128), 0, stream>>>(rbuf, wbuf, kbuf, vbuf, kkbuf, abuf, Scbuf, obuf);

    // ---- epilogue ----
    postproc<<<dim3(16384), blk, 0, stream>>>(obuf, rbuf, kbuf, vbuf, gbuf, r_k, gn_w, gn_b, og_h, og_l);
    mgemm<0, 0><<<dim3(32, 16), blk, 0, stream>>>(og_h, og_l, oT_h, oT_l, (float*)d_out, nullptr, nullptr,
                                                  4096, 1024, 1024, nullptr, nullptr, nullptr);
}

// Round 8
// 650.591 us; speedup vs baseline: 7.7248x; 1.1835x over previous
//
#include <hip/hip_runtime.h>
#include <cstddef>
#include <cstdint>

#define T_ 2048
#define H_ 1024
#define NH_ 16
#define LCTX 512
#define NC 32     // number of chunks
#define CL 64     // chunk length (NC*CL == T_)

typedef __attribute__((ext_vector_type(4))) float f4;
typedef __attribute__((ext_vector_type(4))) unsigned short u16x4;
typedef __attribute__((ext_vector_type(8))) short bf16x8;
typedef __attribute__((ext_vector_type(4))) float f32x4;

#define REP16(X) X(0) X(1) X(2) X(3) X(4) X(5) X(6) X(7) X(8) X(9) X(10) X(11) X(12) X(13) X(14) X(15)
#define REP8(X) X(0) X(1) X(2) X(3) X(4) X(5) X(6) X(7)

__device__ __forceinline__ float sgm(float x) { return 1.0f / (1.0f + expf(-x)); }
__device__ __forceinline__ f4 f4splat(float v) { f4 r; r.x = v; r.y = v; r.z = v; r.w = v; return r; }
__device__ __forceinline__ float hsum4(f4 v) { return (v.x + v.y) + (v.z + v.w); }

__device__ __forceinline__ unsigned short f2bf(float x) {   // RNE (weights, one-time)
    unsigned u = __float_as_uint(x);
    u += 0x7FFFu + ((u >> 16) & 1u);
    return (unsigned short)(u >> 16);
}
__device__ __forceinline__ float bf2f(unsigned short h) {
    return __uint_as_float(((unsigned)h) << 16);
}

// truncation split: x ~= hi + lo, |err| <= 2^-16 |x|
__device__ __forceinline__ void split1(float x, unsigned short& h, unsigned short& l) {
    unsigned u = __float_as_uint(x);
    h = (unsigned short)(u >> 16);
    float r = x - __uint_as_float(u & 0xFFFF0000u);
    l = (unsigned short)(__float_as_uint(r) >> 16);
}
__device__ __forceinline__ void split4(f4 v, u16x4& h, u16x4& l) {
    unsigned short hh, ll;
    split1(v.x, hh, ll); h.x = hh; l.x = ll;
    split1(v.y, hh, ll); h.y = hh; l.y = ll;
    split1(v.z, hh, ll); h.z = hh; l.z = ll;
    split1(v.w, hh, ll); h.w = hh; l.w = ll;
}

// Panel-tiled layout: [M/16][K/32] panels of 512 u16, panel = [gg 4][rr 16][ee 8];
// element (row,k): gg=((k&31)&15)>>2, ee=((k&31)>>4)*4 + (k&3). Matches MFMA frag order.
// Offset (u16) for a 4-aligned k (c4): base of u16x4.
__device__ __forceinline__ size_t toff4(int row, int c4, int kpan) {
    const int j = c4 & 31;
    return ((size_t)(row >> 4) * kpan + (c4 >> 5)) * 512
         + ((j & 15) >> 2) * 128 + (row & 15) * 8 + ((j >> 4) << 2);
}
__device__ __forceinline__ size_t toff1(int row, int k, int kpan) {
    const int j = k & 31;
    return ((size_t)(row >> 4) * kpan + (k >> 5)) * 512
         + ((j & 15) >> 2) * 128 + (row & 15) * 8 + ((j >> 4) << 2) + (j & 3);
}

__device__ __forceinline__ void gload16(const void* g, void* l) {
    __builtin_amdgcn_global_load_lds(
        (const __attribute__((address_space(1))) unsigned int*)g,
        (__attribute__((address_space(3))) unsigned int*)l, 16, 0, 0);
}

// ---------------- fused weight transpose + RNE split -> panel-tiled BT ----------------
struct WSeg { const float* W; unsigned short* Th; unsigned short* Tl;
              int K, N, kpan, tile0, tilesN; };
struct WAll { WSeg s[13]; };

__global__ __launch_bounds__(256) void wtrans_all(WAll all)
{
    const int bid = blockIdx.x;
    int si = 0;
    #pragma unroll
    for (int i = 1; i < 13; ++i) if (bid >= all.s[i].tile0) si = i;
    const WSeg sg = all.s[si];
    const int local = bid - sg.tile0;
    const int k0 = (local / sg.tilesN) * 32;
    const int n0 = (local % sg.tilesN) * 32;

    __shared__ float tile[32][33];
    const int t = threadIdx.x;
    const int r = t >> 3, c4 = (t & 7) * 4;
    f4 v = f4splat(0.0f);
    if (k0 + r < sg.K && n0 + c4 < sg.N)
        v = *(const f4*)(sg.W + (size_t)(k0 + r) * sg.N + n0 + c4);
    tile[r][c4 + 0] = v.x; tile[r][c4 + 1] = v.y;
    tile[r][c4 + 2] = v.z; tile[r][c4 + 3] = v.w;
    __syncthreads();
    // write BT[n][k] panel-tiled (padded region -> zeros)
    {
        const int n = n0 + r;
        float x0 = tile[c4 + 0][r], x1 = tile[c4 + 1][r];
        float x2 = tile[c4 + 2][r], x3 = tile[c4 + 3][r];
        u16x4 hv, lv;
        hv.x = f2bf(x0); lv.x = f2bf(x0 - bf2f(hv.x));
        hv.y = f2bf(x1); lv.y = f2bf(x1 - bf2f(hv.y));
        hv.z = f2bf(x2); lv.z = f2bf(x2 - bf2f(hv.z));
        hv.w = f2bf(x3); lv.w = f2bf(x3 - bf2f(hv.w));
        const size_t off = toff4(n, k0 + c4, sg.kpan);
        *(u16x4*)(sg.Th + off) = hv;
        *(u16x4*)(sg.Tl + off) = lv;
    }
}

// context fp32 [1024][768] -> panel-tiled split pair
__global__ __launch_bounds__(256) void ctx_split(
    const float* __restrict__ X, unsigned short* __restrict__ H,
    unsigned short* __restrict__ L)
{
    const int gid = blockIdx.x * 256 + threadIdx.x;   // 196608 f4 chunks
    const int row = gid / 192;
    const int c4 = (gid - row * 192) * 4;
    f4 v = *(const f4*)(X + (size_t)row * 768 + c4);
    u16x4 h, l; split4(v, h, l);
    const size_t off = toff4(row, c4, 24);
    *(u16x4*)(H + off) = h; *(u16x4*)(L + off) = l;
}

// ---------------- elementwise prep (outputs panel-tiled hi/lo bf16) ----------------
__global__ __launch_bounds__(256) void hs_lerp4(
    const float* __restrict__ hs,
    const float* __restrict__ x_r, const float* __restrict__ x_w,
    const float* __restrict__ x_a, const float* __restrict__ x_g,
    unsigned short* __restrict__ xr_h, unsigned short* __restrict__ xr_l,
    unsigned short* __restrict__ xw_h, unsigned short* __restrict__ xw_l,
    unsigned short* __restrict__ xa_h, unsigned short* __restrict__ xa_l,
    unsigned short* __restrict__ xg_h, unsigned short* __restrict__ xg_l)
{
    const int gid = blockIdx.x * 256 + threadIdx.x;   // 1,048,576 f4 chunks
    const int c4 = (gid & 255) * 4;
    const int row = gid >> 8;
    const int tt = row & (T_ - 1);
    const f4 cur = *(const f4*)(hs + (size_t)row * H_ + c4);
    f4 prev = f4splat(0.0f);
    if (tt) prev = *(const f4*)(hs + (size_t)(row - 1) * H_ + c4);
    const f4 d = prev - cur;
    const size_t off = toff4(row, c4, 32);
    u16x4 h, l;
    split4(cur + d * (*(const f4*)(x_r + c4)), h, l);
    *(u16x4*)(xr_h + off) = h; *(u16x4*)(xr_l + off) = l;
    split4(cur + d * (*(const f4*)(x_w + c4)), h, l);
    *(u16x4*)(xw_h + off) = h; *(u16x4*)(xw_l + off) = l;
    split4(cur + d * (*(const f4*)(x_a + c4)), h, l);
    *(u16x4*)(xa_h + off) = h; *(u16x4*)(xa_l + off) = l;
    split4(cur + d * (*(const f4*)(x_g + c4)), h, l);
    *(u16x4*)(xg_h + off) = h; *(u16x4*)(xg_l + off) = l;
}

__device__ __forceinline__ f4 ctx_sample(const float* __restrict__ cp, int b, int t, int c4) {
    const float scale = (float)(511.0 / 2047.0);
    float tf = (float)t * scale;
    int lo = (int)tf;
    float f = tf - (float)lo;
    int hi = lo + 1; if (hi > LCTX - 1) hi = LCTX - 1;
    f4 cl = *(const f4*)(cp + (size_t)(b * LCTX + lo) * 1024 + c4);
    f4 ch = *(const f4*)(cp + (size_t)(b * LCTX + hi) * 1024 + c4);
    return cl + (ch - cl) * f;
}

__global__ __launch_bounds__(256) void ctx_lerp2(
    const float* __restrict__ cp,
    const float* __restrict__ x_k, const float* __restrict__ x_v,
    unsigned short* __restrict__ xk_h, unsigned short* __restrict__ xk_l,
    unsigned short* __restrict__ xv_h, unsigned short* __restrict__ xv_l)
{
    const int gid = blockIdx.x * 256 + threadIdx.x;
    const int c4 = (gid & 255) * 4;
    const int row = gid >> 8;
    const int b = row >> 11;
    const int tt = row & (T_ - 1);
    const f4 cur = ctx_sample(cp, b, tt, c4);
    f4 prev = f4splat(0.0f);
    if (tt) prev = ctx_sample(cp, b, tt - 1, c4);
    const f4 d = prev - cur;
    const size_t off = toff4(row, c4, 32);
    u16x4 h, l;
    split4(cur + d * (*(const f4*)(x_k + c4)), h, l);
    *(u16x4*)(xk_h + off) = h; *(u16x4*)(xk_l + off) = l;
    split4(cur + d * (*(const f4*)(x_v + c4)), h, l);
    *(u16x4*)(xv_h + off) = h; *(u16x4*)(xv_l + off) = l;
}

// ---------------- MFMA GEMM: A,B panel-tiled split pairs; global_load_lds staging ----
// Tile 128x64, 4 waves, 2 blocks/CU. acc += Ah*Bh + Ah*Bl + Al*Bh.
// EPI: 0 plain, 1 LOGW*sgm(x+b), 2 sgm(x+b), 3 v-lerp, 4 tanh, 5 sgm
// OSPLIT: 1 -> store hi/lo panel-tiled pair (kpanC panels) instead of fp32 row-major
struct GArgs {
    const unsigned short* ATh; const unsigned short* ATl;
    const unsigned short* BTh; const unsigned short* BTl;
    float* C; unsigned short* Ch; unsigned short* Cl;
};
template <int EPI, int OSPLIT>
__global__ __launch_bounds__(256, 2) void mgemm(
    GArgs g0, GArgs g1, GArgs g2,
    int M, int N, int K, int kpanC,
    const float* __restrict__ bias, const float* __restrict__ aux1,
    const float* __restrict__ aux2)
{
    __shared__ __align__(16) unsigned short Ah_[8 * 512];
    __shared__ __align__(16) unsigned short Al_[8 * 512];
    __shared__ __align__(16) unsigned short Bh_[4 * 512];
    __shared__ __align__(16) unsigned short Bl_[4 * 512];
    const GArgs G = blockIdx.z == 0 ? g0 : (blockIdx.z == 1 ? g1 : g2);
    const int tid = threadIdx.x;
    const int lane = tid & 63;
    const int wave = tid >> 6;
    const int bm = blockIdx.x * 128;
    const int bn = blockIdx.y * 64;
    const int kpan = K >> 5;
    const int g = lane >> 4, rr = lane & 15;
    const int sA0 = wave, sA1 = wave + 4;

    f32x4 acc[4][2];
    #pragma unroll
    for (int mi = 0; mi < 4; ++mi)
        #pragma unroll
        for (int ni = 0; ni < 2; ++ni)
            acc[mi][ni] = (f32x4)(0.0f);

    const size_t aBase0 = (size_t)((bm >> 4) + sA0) * kpan * 512;
    const size_t aBase1 = (size_t)((bm >> 4) + sA1) * kpan * 512;
    const size_t bBase  = (size_t)((bn >> 4) + wave) * kpan * 512;

    for (int k0 = 0; k0 < K; k0 += 32) {
        const size_t kp = (size_t)(k0 >> 5) * 512 + (size_t)lane * 8;
        gload16(G.ATh + aBase0 + kp, &Ah_[sA0 * 512]);
        gload16(G.ATh + aBase1 + kp, &Ah_[sA1 * 512]);
        gload16(G.ATl + aBase0 + kp, &Al_[sA0 * 512]);
        gload16(G.ATl + aBase1 + kp, &Al_[sA1 * 512]);
        gload16(G.BTh + bBase + kp, &Bh_[wave * 512]);
        gload16(G.BTl + bBase + kp, &Bl_[wave * 512]);
        __syncthreads();
        bf16x8 a_h[4], a_l[4], b_h[2], b_l[2];
        #pragma unroll
        for (int mi = 0; mi < 4; ++mi) {
            const int s = (wave >> 1) * 4 + mi;
            a_h[mi] = *(const bf16x8*)&Ah_[s * 512 + g * 128 + rr * 8];
            a_l[mi] = *(const bf16x8*)&Al_[s * 512 + g * 128 + rr * 8];
        }
        #pragma unroll
        for (int ni = 0; ni < 2; ++ni) {
            const int s = (wave & 1) * 2 + ni;
            b_h[ni] = *(const bf16x8*)&Bh_[s * 512 + g * 128 + rr * 8];
            b_l[ni] = *(const bf16x8*)&Bl_[s * 512 + g * 128 + rr * 8];
        }
        #pragma unroll
        for (int mi = 0; mi < 4; ++mi)
            #pragma unroll
            for (int ni = 0; ni < 2; ++ni) {
                acc[mi][ni] = __builtin_amdgcn_mfma_f32_16x16x32_bf16(a_h[mi], b_h[ni], acc[mi][ni], 0, 0, 0);
                acc[mi][ni] = __builtin_amdgcn_mfma_f32_16x16x32_bf16(a_h[mi], b_l[ni], acc[mi][ni], 0, 0, 0);
                acc[mi][ni] = __builtin_amdgcn_mfma_f32_16x16x32_bf16(a_l[mi], b_h[ni], acc[mi][ni], 0, 0, 0);
            }
        __syncthreads();
    }
    const int wm = (wave >> 1) * 64;
    const int wn = (wave & 1) * 32;
    #pragma unroll
    for (int mi = 0; mi < 4; ++mi)
        #pragma unroll
        for (int ni = 0; ni < 2; ++ni)
            #pragma unroll
            for (int q = 0; q < 4; ++q) {
                const int grow = bm + wm + mi * 16 + g * 4 + q;
                const int gcol = bn + wn + ni * 16 + rr;
                float x = acc[mi][ni][q];
                if (EPI == 1) x = -0.6065306597126334f * sgm(x + bias[gcol]);
                else if (EPI == 2) x = sgm(x + bias[gcol]);
                else if (EPI == 3) {
                    const size_t o3 = (size_t)grow * N + gcol;
                    float vt = aux1[o3];
                    x = vt + sgm(x + bias[gcol]) * (aux2[o3] - vt);
                }
                else if (EPI == 4) x = tanhf(x);
                else if (EPI == 5) x = sgm(x);
                if (OSPLIT) {
                    if (gcol < kpanC * 32) {
                        unsigned short hh, ll;
                        split1(x, hh, ll);
                        const size_t off = toff1(grow, gcol, kpanC);
                        G.Ch[off] = hh; G.Cl[off] = ll;
                    }
                } else {
                    if (gcol < N) G.C[(size_t)grow * N + gcol] = x;
                }
            }
}

// kk = normalize_per_head(k * k_k); k <- k * (1 + (a-1)*k_a)   (in place)
__global__ __launch_bounds__(256) void prep_k(
    float* __restrict__ k, const float* __restrict__ a,
    const float* __restrict__ k_k, const float* __restrict__ k_a,
    float* __restrict__ kk)
{
    const int gid = blockIdx.x * 256 + threadIdx.x;
    const int j = gid & 63;
    const int h = (gid >> 6) & (NH_ - 1);
    const int ch = h * 64 + j;
    const float kv = k[gid];
    float kkv = kv * k_k[ch];
    float ss = kkv * kkv;
    #pragma unroll
    for (int m = 32; m; m >>= 1) ss += __shfl_xor(ss, m, 64);
    const float nrm = fmaxf(sqrtf(ss), 1e-12f);
    kk[gid] = kkv / nrm;
    const float av = a[gid];
    k[gid] = kv * (1.0f + (av - 1.0f) * k_a[ch]);
}

// ---------------- Chunked RWKV7 scan (unchanged from round 7) ----------------
__global__ __launch_bounds__(128, 1) void chunk_AU(
    const float* __restrict__ w, const float* __restrict__ k,
    const float* __restrict__ v, const float* __restrict__ kk,
    const float* __restrict__ a,
    float* __restrict__ Pbuf, float* __restrict__ Ubuf)
{
    const int bid = blockIdx.x;
    const int c = bid & (NC - 1);
    const int bh = bid >> 5;
    const int b = bh >> 4, h = bh & (NH_ - 1);
    const int tid = threadIdx.x;
    const int wv_ = tid >> 6;        // 0 = Q-wave, 1 = U-wave
    const int lane = tid & 63;
    __shared__ __align__(16) float ew_s[64], ah_s[64], bh_s[64], kh_s[64];

#define DECL_X(i) f4 x##i = f4splat(0.0f);
    REP16(DECL_X)
#undef DECL_X
    if (wv_ == 0) {
#define INIT_Q(i) \
        if (lane == 4*i+0) x##i.x = 1.0f; \
        else if (lane == 4*i+1) x##i.y = 1.0f; \
        else if (lane == 4*i+2) x##i.z = 1.0f; \
        else if (lane == 4*i+3) x##i.w = 1.0f;
        REP16(INIT_Q)
#undef INIT_Q
    }

    size_t idx = (((size_t)b * T_ + (size_t)c * CL) * NH_ + h) * 64 + lane;
    float wvv = 0, kkv = 0, av = 0, kv = 0, vvv = 0;
    if (wv_ == 0) { wvv = w[idx]; kkv = kk[idx]; av = a[idx]; }
    else          { kv = k[idx]; vvv = v[idx]; }

    for (int t = 0; t < CL; ++t) {
        if (wv_ == 0) {
            ew_s[lane] = expf(wvv);
            ah_s[lane] = -kkv;
            bh_s[lane] = kkv * av;
        } else {
            kh_s[lane] = kv;
        }
        const float vcur = vvv;
        __syncthreads();
        if (t + 1 < CL) {
            idx += NH_ * 64;
            if (wv_ == 0) { wvv = w[idx]; kkv = kk[idx]; av = a[idx]; }
            else          { kv = k[idx]; vvv = v[idx]; }
        }
        const f4* A4 = (const f4*)ah_s;
        f4 da = f4splat(0.0f);
#define DOT_(i) { da += x##i * A4[i]; }
        REP16(DOT_)
#undef DOT_
        const float Da = hsum4(da);
        const f4* E4 = (const f4*)ew_s;
        const f4* B4 = (const f4*)bh_s;
        if (wv_ == 0) {
#define UPDQ_(i) { x##i = x##i * E4[i] + Da * B4[i]; }
            REP16(UPDQ_)
#undef UPDQ_
        } else {
            const f4* K4 = (const f4*)kh_s;
#define UPDU_(i) { x##i = x##i * E4[i] + Da * B4[i] + vcur * K4[i]; }
            REP16(UPDU_)
#undef UPDU_
        }
        __syncthreads();
    }
    float* Dst = (wv_ == 0 ? Pbuf : Ubuf) + (((size_t)bh * NC + c) * 64 + lane) * 64;
#define ST_(i) ((f4*)Dst)[i] = x##i;
    REP16(ST_)
#undef ST_
}

__global__ __launch_bounds__(256) void chunk_scan(
    const float* __restrict__ Pbuf, const float* __restrict__ Ubuf,
    float* __restrict__ Scbuf)
{
    const int blk = blockIdx.x;
    const int bh = blk >> 2;
    const int rg = blk & 3;
    const int tid = threadIdx.x;
    const int w = tid >> 6, j = tid & 63;
    const int r0 = rg * 16 + w * 4;
    __shared__ __align__(16) float P_lds[64 * 64];
    __shared__ __align__(16) f4 s4_lds[4][64];

    float a0 = 0, a1 = 0, a2 = 0, a3 = 0;
    {
        const float* Pb = Pbuf + ((size_t)bh * NC + 0) * 4096 + tid * 16;
        #pragma unroll
        for (int i = 0; i < 4; ++i)
            *(f4*)&P_lds[tid * 16 + i * 4] = *(const f4*)(Pb + i * 4);
    }
    for (int c = 0; c < NC; ++c) {
        f4 sv; sv.x = a0; sv.y = a1; sv.z = a2; sv.w = a3;
        s4_lds[w][j] = sv;
        {
            float* Sb = Scbuf + ((size_t)bh * NC + c) * 4096 + r0 * 64 + j;
            Sb[0] = a0; Sb[64] = a1; Sb[128] = a2; Sb[192] = a3;
        }
        const float* Ub = Ubuf + ((size_t)bh * NC + c) * 4096 + r0 * 64 + j;
        float n0 = Ub[0], n1 = Ub[64], n2 = Ub[128], n3 = Ub[192];
        f4 pf0, pf1, pf2, pf3;
        if (c + 1 < NC) {
            const float* Pb = Pbuf + ((size_t)bh * NC + c + 1) * 4096 + tid * 16;
            pf0 = *(const f4*)(Pb + 0); pf1 = *(const f4*)(Pb + 4);
            pf2 = *(const f4*)(Pb + 8); pf3 = *(const f4*)(Pb + 12);
        }
        __syncthreads();
        #pragma unroll 8
        for (int k = 0; k < 64; ++k) {
            const f4 s = s4_lds[w][k];
            const float pv = P_lds[k * 64 + j];
            n0 += s.x * pv; n1 += s.y * pv; n2 += s.z * pv; n3 += s.w * pv;
        }
        a0 = n0; a1 = n1; a2 = n2; a3 = n3;
        __syncthreads();
        if (c + 1 < NC) {
            *(f4*)&P_lds[tid * 16 + 0]  = pf0;
            *(f4*)&P_lds[tid * 16 + 4]  = pf1;
            *(f4*)&P_lds[tid * 16 + 8]  = pf2;
            *(f4*)&P_lds[tid * 16 + 12] = pf3;
        }
    }
}

__global__ __launch_bounds__(128, 1) void chunk_out(
    const float* __restrict__ r, const float* __restrict__ w,
    const float* __restrict__ k, const float* __restrict__ v,
    const float* __restrict__ kk, const float* __restrict__ a,
    const float* __restrict__ Scbuf, float* __restrict__ o)
{
    const int bid = blockIdx.x;
    const int c = bid & (NC - 1);
    const int bh = bid >> 5;
    const int b = bh >> 4, h = bh & (NH_ - 1);
    const int tid = threadIdx.x;
    const int wv_ = tid >> 6;
    const int lane = tid & 63;
    __shared__ __align__(16) float ew_s[64], ah_s[64], bh_s[64], kh_s[64], rh_s[64];
    __shared__ float sa_part[2][64];
    __shared__ float op_part[64];

#define DECL_S(i) f4 s##i;
    REP8(DECL_S)
#undef DECL_S
    const f4* Srow = (const f4*)(Scbuf + (((size_t)bh * NC + c) * 64 + lane) * 64 + wv_ * 32);
#define LD_S(i) s##i = Srow[i];
    REP8(LD_S)
#undef LD_S

    size_t idx = (((size_t)b * T_ + (size_t)c * CL) * NH_ + h) * 64 + lane;
    float wvv = 0, kkv = 0, av = 0, kv = 0, rv = 0, vvv;
    if (wv_ == 0) { wvv = w[idx]; kkv = kk[idx]; av = a[idx]; }
    else          { kv = k[idx]; rv = r[idx]; }
    vvv = v[idx];

    float oprev = 0.0f;
    size_t oprev_idx = 0;

    for (int t = 0; t < CL; ++t) {
        if (t > 0 && wv_ == 0) o[oprev_idx] = oprev + op_part[lane];
        if (wv_ == 0) {
            ew_s[lane] = expf(wvv);
            ah_s[lane] = -kkv;
            bh_s[lane] = kkv * av;
        } else {
            kh_s[lane] = kv;
            rh_s[lane] = rv;
        }
        const float vcur = vvv;
        const size_t oidx = idx;
        __syncthreads();
        if (t + 1 < CL) {
            idx += NH_ * 64;
            if (wv_ == 0) { wvv = w[idx]; kkv = kk[idx]; av = a[idx]; }
            else          { kv = k[idx]; rv = r[idx]; }
            vvv = v[idx];
        }
        const f4* A4 = (const f4*)(ah_s + wv_ * 32);
        f4 ua = f4splat(0.0f);
#define DOTS_(i) { ua += s##i * A4[i]; }
        REP8(DOTS_)
#undef DOTS_
        sa_part[wv_][lane] = hsum4(ua);
        __syncthreads();
        const float sa = sa_part[0][lane] + sa_part[1][lane];
        const f4* E4 = (const f4*)(ew_s + wv_ * 32);
        const f4* B4 = (const f4*)(bh_s + wv_ * 32);
        const f4* K4 = (const f4*)(kh_s + wv_ * 32);
        const f4* R4 = (const f4*)(rh_s + wv_ * 32);
        f4 oa = f4splat(0.0f);
#define UPDO_(i) { s##i = s##i * E4[i] + sa * B4[i] + vcur * K4[i]; oa += s##i * R4[i]; }
        REP8(UPDO_)
#undef UPDO_
        const float o_w = hsum4(oa);
        if (wv_ == 1) op_part[lane] = o_w;
        else { oprev = o_w; oprev_idx = oidx; }
        __syncthreads();
    }
    if (wv_ == 0) o[oprev_idx] = oprev + op_part[lane];
}

// GroupNorm(64) + r_k readout + output gate -> og (panel-tiled split pair)
__global__ __launch_bounds__(256) void postproc(
    const float* __restrict__ o, const float* __restrict__ r, const float* __restrict__ k,
    const float* __restrict__ v, const float* __restrict__ g, const float* __restrict__ r_k,
    const float* __restrict__ gn_w, const float* __restrict__ gn_b,
    unsigned short* __restrict__ og_h, unsigned short* __restrict__ og_l)
{
    const int gid = blockIdx.x * 256 + threadIdx.x;
    const int i = gid & 63;
    const int h = (gid >> 6) & (NH_ - 1);
    const int ch = h * 64 + i;
    const float ov = o[gid];
    float s1 = ov, s2 = ov * ov;
    float term = r[gid] * k[gid] * r_k[ch];
    #pragma unroll
    for (int m = 32; m; m >>= 1) {
        s1 += __shfl_xor(s1, m, 64);
        s2 += __shfl_xor(s2, m, 64);
        term += __shfl_xor(term, m, 64);
    }
    const float mu = s1 * (1.0f / 64.0f);
    const float var = s2 * (1.0f / 64.0f) - mu * mu;
    const float on = (ov - mu) * rsqrtf(var + 6.4e-4f);
    const float outv = (on * gn_w[ch] + gn_b[ch] + term * v[gid]) * g[gid];
    unsigned short hh, ll;
    split1(outv, hh, ll);
    const int row = gid >> 10;
    const int col = gid & 1023;
    const size_t off = toff1(row, col, 32);
    og_h[off] = hh; og_l[off] = ll;
}

extern "C" void kernel_launch(void* const* d_in, const int* in_sizes, int n_in,
                              void* d_out, int out_size, void* d_ws, size_t ws_size,
                              hipStream_t stream)
{
    const float* hs      = (const float*)d_in[0];
    const float* context = (const float*)d_in[1];
    const float* v_first = (const float*)d_in[2];
    const float* x_r = (const float*)d_in[3];
    const float* x_w = (const float*)d_in[4];
    const float* x_k = (const float*)d_in[5];
    const float* x_v = (const float*)d_in[6];
    const float* x_a = (const float*)d_in[7];
    const float* x_g = (const float*)d_in[8];
    const float* k_k = (const float*)d_in[9];
    const float* k_a = (const float*)d_in[10];
    const float* r_k = (const float*)d_in[11];
    const float* W_r = (const float*)d_in[12];
    const float* W_k = (const float*)d_in[13];
    const float* W_v = (const float*)d_in[14];
    const float* W_o = (const float*)d_in[15];
    const float* W_cond = (const float*)d_in[16];
    const float* wA = (const float*)d_in[17];
    const float* wB = (const float*)d_in[18];
    const float* wb = (const float*)d_in[19];
    const float* aA = (const float*)d_in[20];
    const float* aB = (const float*)d_in[21];
    const float* ab = (const float*)d_in[22];
    const float* gA = (const float*)d_in[23];
    const float* gB = (const float*)d_in[24];
    const float* vA = (const float*)d_in[25];
    const float* vB = (const float*)d_in[26];
    const float* vb = (const float*)d_in[27];
    const float* gn_w = (const float*)d_in[28];
    const float* gn_b = (const float*)d_in[29];
    (void)in_sizes; (void)n_in; (void)out_size; (void)ws_size;

    float* ws = (float*)d_ws;
    float* cp    = ws;                   // [1024,1024] f32
    float* rbuf  = cp    + (1 << 20);
    float* kbuf  = rbuf  + (4 << 20);
    float* vtmp  = kbuf  + (4 << 20);    // raw v; later Ubuf
    float* wbuf  = vtmp  + (4 << 20);    // log-decay w; later og pair
    float* abuf  = wbuf  + (4 << 20);
    float* obuf  = abuf  + (4 << 20);    // alias xr pair
    float* Pbuf  = obuf  + (4 << 20);    // alias xw pair
    float* Scbuf = Pbuf  + (4 << 20);    // alias xa pair
    float* kkbuf = Scbuf + (4 << 20);    // alias xk pair
    float* gbuf  = kkbuf + (4 << 20);    // alias xg pair
    float* vbuf  = gbuf  + (4 << 20);    // alias xv pair
    float* endf  = vbuf  + (4 << 20);
    float* Ubuf  = vtmp;

    unsigned short* xr_h = (unsigned short*)obuf;  unsigned short* xr_l = xr_h + (4 << 20);
    unsigned short* xw_h = (unsigned short*)Pbuf;  unsigned short* xw_l = xw_h + (4 << 20);
    unsigned short* xa_h = (unsigned short*)Scbuf; unsigned short* xa_l = xa_h + (4 << 20);
    unsigned short* xk_h = (unsigned short*)kkbuf; unsigned short* xk_l = xk_h + (4 << 20);
    unsigned short* xg_h = (unsigned short*)gbuf;  unsigned short* xg_l = xg_h + (4 << 20);
    unsigned short* xv_h = (unsigned short*)vbuf;  unsigned short* xv_l = xv_h + (4 << 20);
    unsigned short* og_h = (unsigned short*)wbuf;  unsigned short* og_l = og_h + (4 << 20);

    unsigned short* u = (unsigned short*)endf;
    unsigned short* ctx_h = u;  u += 786432;
    unsigned short* ctx_l = u;  u += 786432;
    unsigned short* w1h = u;    u += 262144;
    unsigned short* w1l = u;    u += 262144;
    unsigned short* a1h = u;    u += 262144;
    unsigned short* a1l = u;    u += 262144;
    unsigned short* g1h = u;    u += 524288;
    unsigned short* g1l = u;    u += 524288;
    unsigned short* v1h = u;    u += 131072;
    unsigned short* v1l = u;    u += 131072;
    unsigned short* condT_h = u; u += 786432;
    unsigned short* condT_l = u; u += 786432;
    unsigned short* rT_h = u;    u += 1048576;
    unsigned short* rT_l = u;    u += 1048576;
    unsigned short* kT_h = u;    u += 1048576;
    unsigned short* kT_l = u;    u += 1048576;
    unsigned short* vT_h = u;    u += 1048576;
    unsigned short* vT_l = u;    u += 1048576;
    unsigned short* oT_h = u;    u += 1048576;
    unsigned short* oT_l = u;    u += 1048576;
    unsigned short* waT_h = u;   u += 65536;
    unsigned short* waT_l = u;   u += 65536;
    unsigned short* wbT_h = u;   u += 65536;
    unsigned short* wbT_l = u;   u += 65536;
    unsigned short* aaT_h = u;   u += 65536;
    unsigned short* aaT_l = u;   u += 65536;
    unsigned short* abT_h = u;   u += 65536;
    unsigned short* abT_l = u;   u += 65536;
    unsigned short* gaT_h = u;   u += 131072;
    unsigned short* gaT_l = u;   u += 131072;
    unsigned short* gbT_h = u;   u += 131072;
    unsigned short* gbT_l = u;   u += 131072;
    unsigned short* vaT_h = u;   u += 65536;   // N padded 16->64
    unsigned short* vaT_l = u;   u += 65536;
    unsigned short* vbT_h = u;   u += 32768;   // K padded 16->32
    unsigned short* vbT_l = u;   u += 32768;

    const dim3 blk(256);
    // ---- fused weight transposes + RNE split -> panel-tiled (padded) ----
    {
        WAll all;
        auto seg = [](const float* W, unsigned short* Th, unsigned short* Tl,
                      int K, int N, int Kpad, int Npad, int tile0) {
            WSeg s; s.W = W; s.Th = Th; s.Tl = Tl; s.K = K; s.N = N;
            s.kpan = Kpad / 32; s.tile0 = tile0; s.tilesN = Npad / 32; return s;
        };
        int t0 = 0;
        all.s[0]  = seg(W_cond, condT_h, condT_l, 768, 1024, 768, 1024, t0);  t0 += 24 * 32;
        all.s[1]  = seg(W_r, rT_h, rT_l, 1024, 1024, 1024, 1024, t0);         t0 += 32 * 32;
        all.s[2]  = seg(W_k, kT_h, kT_l, 1024, 1024, 1024, 1024, t0);         t0 += 32 * 32;
        all.s[3]  = seg(W_v, vT_h, vT_l, 1024, 1024, 1024, 1024, t0);         t0 += 32 * 32;
        all.s[4]  = seg(W_o, oT_h, oT_l, 1024, 1024, 1024, 1024, t0);         t0 += 32 * 32;
        all.s[5]  = seg(wA, waT_h, waT_l, 1024, 64, 1024, 64, t0);            t0 += 32 * 2;
        all.s[6]  = seg(wB, wbT_h, wbT_l, 64, 1024, 64, 1024, t0);            t0 += 2 * 32;
        all.s[7]  = seg(aA, aaT_h, aaT_l, 1024, 64, 1024, 64, t0);            t0 += 32 * 2;
        all.s[8]  = seg(aB, abT_h, abT_l, 64, 1024, 64, 1024, t0);            t0 += 2 * 32;
        all.s[9]  = seg(gA, gaT_h, gaT_l, 1024, 128, 1024, 128, t0);          t0 += 32 * 4;
        all.s[10] = seg(gB, gbT_h, gbT_l, 128, 1024, 128, 1024, t0);          t0 += 4 * 32;
        all.s[11] = seg(vA, vaT_h, vaT_l, 1024, 16, 1024, 64, t0);            t0 += 32 * 2;
        all.s[12] = seg(vB, vbT_h, vbT_l, 16, 1024, 32, 1024, t0);            t0 += 1 * 32;
        wtrans_all<<<dim3(t0), blk, 0, stream>>>(all);
    }

    auto GA = [](const unsigned short* ah, const unsigned short* al,
                 const unsigned short* bh, const unsigned short* bl,
                 float* c, unsigned short* ch, unsigned short* cl) {
        GArgs g; g.ATh = ah; g.ATl = al; g.BTh = bh; g.BTl = bl;
        g.C = c; g.Ch = ch; g.Cl = cl; return g;
    };

    // ---- activations (panel-tiled pre-split) ----
    ctx_split<<<dim3(768), blk, 0, stream>>>(context, ctx_h, ctx_l);
    hs_lerp4<<<dim3(4096), blk, 0, stream>>>(hs, x_r, x_w, x_a, x_g,
                                             xr_h, xr_l, xw_h, xw_l, xa_h, xa_l, xg_h, xg_l);
    {
        GArgs gc = GA(ctx_h, ctx_l, condT_h, condT_l, cp, nullptr, nullptr);
        mgemm<0, 0><<<dim3(8, 16, 1), blk, 0, stream>>>(gc, gc, gc, 1024, 1024, 768, 0,
                                                        nullptr, nullptr, nullptr);
    }
    ctx_lerp2<<<dim3(4096), blk, 0, stream>>>(cp, x_k, x_v, xk_h, xk_l, xv_h, xv_l);

    // ---- main projections r/k/v batched over grid.z ----
    {
        GArgs gr = GA(xr_h, xr_l, rT_h, rT_l, rbuf, nullptr, nullptr);
        GArgs gk = GA(xk_h, xk_l, kT_h, kT_l, kbuf, nullptr, nullptr);
        GArgs gv = GA(xv_h, xv_l, vT_h, vT_l, vtmp, nullptr, nullptr);
        mgemm<0, 0><<<dim3(32, 16, 3), blk, 0, stream>>>(gr, gk, gv, 4096, 1024, 1024, 0,
                                                         nullptr, nullptr, nullptr);
    }
    // ---- LoRA stage 1 (panel-tiled split outputs) ----
    {
        GArgs g1_ = GA(xw_h, xw_l, waT_h, waT_l, nullptr, w1h, w1l);
        mgemm<4, 1><<<dim3(32, 1, 1), blk, 0, stream>>>(g1_, g1_, g1_, 4096, 64, 1024, 2,
                                                        nullptr, nullptr, nullptr);
        GArgs g2_ = GA(xa_h, xa_l, aaT_h, aaT_l, nullptr, a1h, a1l);
        mgemm<0, 1><<<dim3(32, 1, 1), blk, 0, stream>>>(g2_, g2_, g2_, 4096, 64, 1024, 2,
                                                        nullptr, nullptr, nullptr);
        GArgs g3_ = GA(xg_h, xg_l, gaT_h, gaT_l, nullptr, g1h, g1l);
        mgemm<5, 1><<<dim3(32, 2, 1), blk, 0, stream>>>(g3_, g3_, g3_, 4096, 128, 1024, 4,
                                                        nullptr, nullptr, nullptr);
        GArgs g4_ = GA(xv_h, xv_l, vaT_h, vaT_l, nullptr, v1h, v1l);
        mgemm<0, 1><<<dim3(32, 1, 1), blk, 0, stream>>>(g4_, g4_, g4_, 4096, 64, 1024, 1,
                                                        nullptr, nullptr, nullptr);
    }
    // ---- LoRA stage 2 ----
    {
        GArgs gw = GA(w1h, w1l, wbT_h, wbT_l, wbuf, nullptr, nullptr);
        mgemm<1, 0><<<dim3(32, 16, 1), blk, 0, stream>>>(gw, gw, gw, 4096, 1024, 64, 0,
                                                         wb, nullptr, nullptr);
        GArgs ga = GA(a1h, a1l, abT_h, abT_l, abuf, nullptr, nullptr);
        mgemm<2, 0><<<dim3(32, 16, 1), blk, 0, stream>>>(ga, ga, ga, 4096, 1024, 64, 0,
                                                         ab, nullptr, nullptr);
        GArgs gg = GA(g1h, g1l, gbT_h, gbT_l, gbuf, nullptr, nullptr);
        mgemm<0, 0><<<dim3(32, 16, 1), blk, 0, stream>>>(gg, gg, gg, 4096, 1024, 128, 0,
                                                         nullptr, nullptr, nullptr);
        GArgs gv2 = GA(v1h, v1l, vbT_h, vbT_l, vbuf, nullptr, nullptr);
        mgemm<3, 0><<<dim3(32, 16, 1), blk, 0, stream>>>(gv2, gv2, gv2, 4096, 1024, 32, 0,
                                                         vb, vtmp, v_first);
    }

    // ---- recurrence ----
    prep_k<<<dim3(16384), blk, 0, stream>>>(kbuf, abuf, k_k, k_a, kkbuf);
    chunk_AU<<<dim3(1024), dim3(128), 0, stream>>>(wbuf, kbuf, vbuf, kkbuf, abuf, Pbuf, Ubuf);
    chunk_scan<<<dim3(128), blk, 0, stream>>>(Pbuf, Ubuf, Scbuf);
    chunk_out<<<dim3(1024), dim3(128), 0, stream>>>(rbuf, wbuf, kbuf, vbuf, kkbuf, abuf, Scbuf, obuf);

    // ---- epilogue ----
    postproc<<<dim3(16384), blk, 0, stream>>>(obuf, rbuf, kbuf, vbuf, gbuf, r_k, gn_w, gn_b, og_h, og_l);
    {
        GArgs go = GA(og_h, og_l, oT_h, oT_l, (float*)d_out, nullptr, nullptr);
        mgemm<0, 0><<<dim3(32, 16, 1), blk, 0, stream>>>(go, go, go, 4096, 1024, 1024, 0,
                                                         nullptr, nullptr, nullptr);
    }
}